// Round 14
// baseline (1243.425 us; speedup 1.0000x reference)
//
#include <hip/hip_runtime.h>
#include <hip/hip_bf16.h>
#include <stdint.h>

typedef __hip_bfloat16 bf16;
typedef __attribute__((ext_vector_type(8))) short bf16x8;
typedef __attribute__((ext_vector_type(4))) float f32x4;

#define DEV static __device__ __forceinline__

DEV float b2f(bf16 v) { return __bfloat162float(v); }
DEV bf16  f2b(float v) { return __float2bfloat16(v); }

DEV float u2f(unsigned short u) {
  unsigned int x = (unsigned int)u << 16;
  float f;
  __builtin_memcpy(&f, &x, 4);
  return f;
}

DEV unsigned short f2u(float v) {
  bf16 b = f2b(v);
  unsigned short u;
  __builtin_memcpy(&u, &b, 2);
  return u;
}

DEV void gload16(const void* g, void* l) {
  __builtin_amdgcn_global_load_lds(
      (__attribute__((address_space(1))) void*)(void*)g,
      (__attribute__((address_space(3))) void*)l, 16, 0, 0);
}

DEV f32x4 mfma16(bf16x8 a, bf16x8 b, f32x4 c) {
  return __builtin_amdgcn_mfma_f32_16x16x32_bf16(a, b, c, 0, 0, 0);
}

// -------- fused embed + layernorm (layer 0): x = emb[tok]*32+pe; h = LN(x) ----
__global__ __launch_bounds__(256) void embed_ln_kernel(
    const int* __restrict__ tok, const float* __restrict__ emb,
    const float* __restrict__ pe, const float* __restrict__ g,
    const float* __restrict__ be, float* __restrict__ x, bf16* __restrict__ h)
{
  const int r = blockIdx.x, t = threadIdx.x;
  const int s = r & 1023;
  const int tk = tok[r];
  const float4 e  = ((const float4*)(emb + (size_t)tk * 1024))[t];
  const float4 pp = ((const float4*)(pe + (size_t)s * 1024))[t];
  float4 v;
  v.x = e.x * 32.0f + pp.x;
  v.y = e.y * 32.0f + pp.y;
  v.z = e.z * 32.0f + pp.z;
  v.w = e.w * 32.0f + pp.w;

  float sm  = v.x + v.y + v.z + v.w;
  float sq = v.x * v.x + v.y * v.y + v.z * v.z + v.w * v.w;
  #pragma unroll
  for (int d = 1; d < 64; d <<= 1) {
    sm += __shfl_xor(sm, d);
    sq += __shfl_xor(sq, d);
  }
  __shared__ float red[8];
  const int w = t >> 6, l = t & 63;
  if (l == 0) { red[w] = sm; red[4 + w] = sq; }
  __syncthreads();
  sm = red[0] + red[1] + red[2] + red[3];
  sq = red[4] + red[5] + red[6] + red[7];
  const float mean = sm * (1.0f / 1024.0f);
  const float var  = sq * (1.0f / 1024.0f) - mean * mean;
  const float inv  = 1.0f / sqrtf(var + 1e-5f);

  ((float4*)(x + (size_t)r * 1024))[t] = v;
  bf16* hp = h + (size_t)r * 1024 + t * 4;
  const float* gp = g + t * 4;
  const float* bp = be + t * 4;
  const float vv[4] = {v.x, v.y, v.z, v.w};
  #pragma unroll
  for (int j = 0; j < 4; ++j)
    hp[j] = f2b((vv[j] - mean) * inv * gp[j] + bp[j]);
}

// -- fused residual + layernorm: x += sum(bf16 P[0..np)) + bias; h = LN(x)*g+be
__global__ __launch_bounds__(256) void ln_res_kernel(
    float* __restrict__ x, const bf16* __restrict__ P, int np,
    const float* __restrict__ bias, const float* __restrict__ g,
    const float* __restrict__ be, bf16* __restrict__ h)
{
  const int r = blockIdx.x, t = threadIdx.x;
  float4 v = ((const float4*)(x + (size_t)r * 1024))[t];
  for (int i = 0; i < np; ++i) {
    const ushort4 pv = ((const ushort4*)(P + ((size_t)i * 2048 + r) * 1024))[t];
    v.x += u2f(pv.x); v.y += u2f(pv.y); v.z += u2f(pv.z); v.w += u2f(pv.w);
  }
  const float4 bv = ((const float4*)bias)[t];
  v.x += bv.x; v.y += bv.y; v.z += bv.z; v.w += bv.w;

  float s  = v.x + v.y + v.z + v.w;
  float sq = v.x * v.x + v.y * v.y + v.z * v.z + v.w * v.w;
  #pragma unroll
  for (int d = 1; d < 64; d <<= 1) {
    s  += __shfl_xor(s, d);
    sq += __shfl_xor(sq, d);
  }
  __shared__ float red[8];
  const int w = t >> 6, l = t & 63;
  if (l == 0) { red[w] = s; red[4 + w] = sq; }
  __syncthreads();
  s  = red[0] + red[1] + red[2] + red[3];
  sq = red[4] + red[5] + red[6] + red[7];
  const float mean = s * (1.0f / 1024.0f);
  const float var  = sq * (1.0f / 1024.0f) - mean * mean;
  const float inv  = 1.0f / sqrtf(var + 1e-5f);

  ((float4*)(x + (size_t)r * 1024))[t] = v;
  bf16* hp = h + (size_t)r * 1024 + t * 4;
  const float* gp = g + t * 4;
  const float* bp = be + t * 4;
  const float vv[4] = {v.x, v.y, v.z, v.w};
  #pragma unroll
  for (int j = 0; j < 4; ++j)
    hp[j] = f2b((vv[j] - mean) * inv * gp[j] + bp[j]);
}

// ------------- 64x64 transpose+cast tile body -------------
DEV void transpose_tile(const float* __restrict__ in, bf16* __restrict__ out,
                        int ldin, int ldout, int r0, int c0, int t)
{
  __shared__ bf16 tile[64][64];
  #pragma unroll
  for (int i = 0; i < 4; ++i) {
    const int r = i * 16 + (t >> 4), c = (t & 15) * 4;
    const float4 v = *(const float4*)&in[(size_t)(r0 + r) * ldin + c0 + c];
    tile[r][c + 0] = f2b(v.x);
    tile[r][c + 1] = f2b(v.y);
    tile[r][c + 2] = f2b(v.z);
    tile[r][c + 3] = f2b(v.w);
  }
  __syncthreads();
  #pragma unroll
  for (int i = 0; i < 2; ++i) {
    const int oc = i * 32 + (t >> 3);
    const int rr = (t & 7) * 8;
    unsigned short tmp[8] __attribute__((aligned(16)));
    #pragma unroll
    for (int j = 0; j < 8; ++j)
      tmp[j] = ((const unsigned short*)tile)[(rr + j) * 64 + oc];
    *(uint4*)&out[(size_t)(c0 + oc) * ldout + r0 + rr] = *(const uint4*)tmp;
  }
}

// generic single-matrix transpose+cast (fallback path for Wout)
__global__ __launch_bounds__(256) void transpose_cast_kernel(
    const float* __restrict__ in, bf16* __restrict__ out, int ldin, int ldout)
{
  transpose_tile(in, out, ldin, ldout, blockIdx.y * 64, blockIdx.x * 64, threadIdx.x);
}

// dispatch one 64x64 tile of the per-layer weight set (3072 tiles/layer)
DEV void prep_dispatch(int wid,
    const float* Wq, const float* Wk, const float* Wv, const float* Wo,
    const float* W1, const float* W2,
    bf16* WqkvT, bf16* WoT, bf16* W1T, bf16* W2T, int t)
{
  const float* src; bf16* dst; int ldin, ldout, tx, ty;
  if (wid < 768) {
    const int m = wid >> 8, tt = wid & 255;
    src = (m == 0) ? Wq : (m == 1) ? Wk : Wv;
    dst = WqkvT + (size_t)m * 1024 * 1024;
    ldin = 1024; ldout = 1024; tx = tt & 15; ty = tt >> 4;
  } else if (wid < 1024) {
    const int tt = wid - 768;
    src = Wo; dst = WoT; ldin = 1024; ldout = 1024; tx = tt & 15; ty = tt >> 4;
  } else if (wid < 2048) {
    const int tt = wid - 1024;
    src = W1; dst = W1T; ldin = 4096; ldout = 1024; tx = tt & 63; ty = tt >> 6;
  } else {
    const int tt = wid - 2048;
    src = W2; dst = W2T; ldin = 1024; ldout = 4096; tx = tt & 15; ty = tt >> 4;
  }
  transpose_tile(src, dst, ldin, ldout, ty * 64, tx * 64, t);
}

// per-layer weight prep (fallback path)
__global__ __launch_bounds__(256) void prep_layer_kernel(
    const float* __restrict__ Wq, const float* __restrict__ Wk,
    const float* __restrict__ Wv, const float* __restrict__ Wo,
    const float* __restrict__ W1, const float* __restrict__ W2,
    bf16* __restrict__ WqkvT, bf16* __restrict__ WoT,
    bf16* __restrict__ W1T, bf16* __restrict__ W2T)
{
  prep_dispatch(blockIdx.x, Wq, Wk, Wv, Wo, W1, W2,
                WqkvT, WoT, W1T, W2T, threadIdx.x);
}

// all-layers weight prep + Wout transpose: 6*3072 + 8000 blocks
__global__ __launch_bounds__(256) void prep_all_kernel(
    const float* __restrict__ Wq, const float* __restrict__ Wk,
    const float* __restrict__ Wv, const float* __restrict__ Wo,
    const float* __restrict__ W1, const float* __restrict__ W2,
    const float* __restrict__ Wout,
    bf16* __restrict__ WqkvT, bf16* __restrict__ WoT,
    bf16* __restrict__ W1T, bf16* __restrict__ W2T,
    bf16* __restrict__ WoutT)
{
  const size_t DD = (size_t)1024 * 1024, DF = (size_t)1024 * 4096;
  if (blockIdx.x >= 6 * 3072) {
    const int tt = blockIdx.x - 6 * 3072;    // 8000 tiles: 1024x32000
    const int tx = tt % 500, ty = tt / 500;
    transpose_tile(Wout, WoutT, 32000, 1024, ty * 64, tx * 64, threadIdx.x);
    return;
  }
  const int layer = blockIdx.x / 3072;
  const int wid = blockIdx.x - layer * 3072;
  prep_dispatch(wid,
      Wq + layer * DD, Wk + layer * DD, Wv + layer * DD, Wo + layer * DD,
      W1 + layer * DF, W2 + layer * DF,
      WqkvT + layer * 3 * DD, WoT + layer * DD,
      W1T + layer * DF, W2T + layer * DF, threadIdx.x);
}

// ------------- pipelined GEMM: C(MxN) = A(MxK,row) * BT(NxK,row)^T -------------
// BM=BN=128, BK=32; 3-buffer single-barrier ring (48 KB LDS -> 3 blocks/CU),
// counted vmcnt(4) (T4), verified conflict-free T2 XOR swizzle.
// Buffer (kt+2)%3 == (kt-1)%3 was lgkm-drained by every wave before the
// barrier at top of kt -> provably dead, one barrier per K-tile.
// EPI: 0 = bf16 store; 1 = +bias f32 store; 2 = gelu(acc+bias) bf16;
//      3 = bf16 K-slice partial store P[z][M][N]; 4 = QKV fused: cols<2048 ->
//          qkv bf16, cols>=2048 -> vT[(b*1024+hk)*1024+s] transposed write
// grid: (M/128, N/128, KSLICES), block 256 (4 waves), K-slice length ksl
template<int EPI, int SWZ>
__global__ __launch_bounds__(256, 3) void gemm_pl(
    const bf16* __restrict__ A, int lda,
    const bf16* __restrict__ BT, int ldb,
    void* __restrict__ Cp, int ldc,
    const float* __restrict__ bias,
    bf16* __restrict__ vTp,
    int ksl)
{
  __shared__ bf16 As[3][4096];
  __shared__ bf16 Bs[3][4096];
  const int t = threadIdx.x;

  int bm, bn;
  if constexpr (SWZ) {                        // XCD-chunked swizzle (nwg%8==0)
    const int nbm = gridDim.x;
    const int nwg = nbm * gridDim.y;
    int wid = blockIdx.x + nbm * blockIdx.y;
    wid = (wid & 7) * (nwg >> 3) + (wid >> 3);
    bm = wid % nbm; bn = wid / nbm;
  } else {
    bm = blockIdx.x; bn = blockIdx.y;
  }

  const int w = t >> 6, l = t & 63;
  const int wr = (w >> 1) * 64, wc = (w & 1) * 64;
  const int l15 = l & 15, l4 = l >> 4;
  const int kbeg = blockIdx.z * ksl;
  const int NT = ksl >> 5;

  // T2: pre-swizzled global column-block; key = (lds_row>>1)&3 = (t>>3)&3
  const int colblk = (((t & 3) ^ ((t >> 3) & 3))) * 8;
  const bf16* gA = A  + (size_t)(bm * 128 + (t >> 2)) * lda + colblk + kbeg;
  const bf16* gB = BT + (size_t)(bn * 128 + (t >> 2)) * ldb + colblk + kbeg;
  const int dst = w * 512;

  auto stage = [&](int tile, int buf) {
    const int k0 = tile * 32;
    gload16(gA + k0, &As[buf][dst]);
    gload16(gA + (size_t)64 * lda + k0, &As[buf][2048 + dst]);
    gload16(gB + k0, &Bs[buf][dst]);
    gload16(gB + (size_t)64 * ldb + k0, &Bs[buf][2048 + dst]);
  };

  f32x4 acc[4][4];
  #pragma unroll
  for (int m = 0; m < 4; ++m)
    #pragma unroll
    for (int n = 0; n < 4; ++n)
      acc[m][n] = (f32x4){0.f, 0.f, 0.f, 0.f};

  stage(0, 0);
  stage(1, 1);

  // T2 read-side swizzle: column-block = l4 ^ ((row>>1)&3); row%16 == l15
  const int rdcol = ((l4 ^ ((l15 >> 1) & 3))) * 8;

  int buf = 0;
  for (int kt = 0; kt < NT; ++kt) {
    // tile kt's 4 loads landed; kt+1's 4 stay in flight (never drain mid-loop)
    if (kt + 1 < NT) asm volatile("s_waitcnt vmcnt(4)" ::: "memory");
    else             asm volatile("s_waitcnt vmcnt(0)" ::: "memory");
    __builtin_amdgcn_s_barrier();            // single barrier per K-tile
    __builtin_amdgcn_sched_barrier(0);

    int nb = buf + 2; if (nb >= 3) nb -= 3;  // ring slot freed at end of kt-1

    bf16x8 af[4], bfr[4];
    #pragma unroll
    for (int m = 0; m < 4; ++m)
      af[m] = *(const bf16x8*)&As[buf][(wr + m * 16 + l15) * 32 + rdcol];
    #pragma unroll
    for (int n = 0; n < 4; ++n)
      bfr[n] = *(const bf16x8*)&Bs[buf][(wc + n * 16 + l15) * 32 + rdcol];
    if (kt + 2 < NT) stage(kt + 2, nb);      // overwrite provably-dead buffer
    asm volatile("s_waitcnt lgkmcnt(0)" ::: "memory");
    __builtin_amdgcn_sched_barrier(0);       // rule #18: pin MFMA below wait

    __builtin_amdgcn_s_setprio(1);
    #pragma unroll
    for (int m = 0; m < 4; ++m)
      #pragma unroll
      for (int n = 0; n < 4; ++n)
        acc[m][n] = mfma16(af[m], bfr[n], acc[m][n]);
    __builtin_amdgcn_s_setprio(0);
    __builtin_amdgcn_sched_barrier(0);

    if (++buf >= 3) buf = 0;
  }

  const int crow = bm * 128 + wr, ccol = bn * 128 + wc;
  #pragma unroll
  for (int n = 0; n < 4; ++n) {
    const int col = ccol + n * 16 + l15;
    float bv = 0.f;
    if (EPI == 1 || EPI == 2) bv = bias[col];
    #pragma unroll
    for (int m = 0; m < 4; ++m) {
      const int row = crow + m * 16 + l4 * 4;
      if (EPI == 4 && ccol >= 2048) {
        // V part: vT[(b*1024 + hk)][s], 4 consecutive s as one 8B store
        const int b = row >> 10, s = row & 1023;
        const int hk = col - 2048;
        ushort4 pk;
        pk.x = f2u(acc[m][n][0]); pk.y = f2u(acc[m][n][1]);
        pk.z = f2u(acc[m][n][2]); pk.w = f2u(acc[m][n][3]);
        *(ushort4*)&vTp[((size_t)b * 1024 + hk) * 1024 + s] = pk;
        continue;
      }
      #pragma unroll
      for (int r = 0; r < 4; ++r) {
        const float v = acc[m][n][r];
        if (EPI == 0 || EPI == 4) {
          ((bf16*)Cp)[(size_t)(row + r) * ldc + col] = f2b(v);
        } else if (EPI == 1) {
          ((float*)Cp)[(size_t)(row + r) * ldc + col] = v + bv;
        } else if (EPI == 2) {
          const float u = v + bv;
          const float gel = 0.5f * u * (1.0f + erff(u * 0.70710678118654752f));
          ((bf16*)Cp)[(size_t)(row + r) * ldc + col] = f2b(gel);
        } else {
          const int M = gridDim.x * 128;
          ((bf16*)Cp)[((size_t)blockIdx.z * M + row + r) * ldc + col] = f2b(v);
        }
      }
    }
  }
}

// ------------- 256x128 8-wave single-barrier GEMM (logits; round-12 best) ----
// 8 waves as 4m x 2n, per-wave 64x64; 3-buffer BK=32 ring (72 KB LDS)
// -> 2 blocks/CU. Counted vmcnt(3). Verified conflict-free XOR swizzle.
// grid: (M/256, N/128), nwg % 8 == 0 (XCD swizzle). 512 threads.
__global__ __launch_bounds__(512, 4) void gemm256(
    const bf16* __restrict__ A, int lda,
    const bf16* __restrict__ BT, int ldb,
    float* __restrict__ C, int ldc,
    const float* __restrict__ bias, int K)
{
  __shared__ bf16 As[3][8192];   // 256 rows x 32 cols per buffer
  __shared__ bf16 Bs[3][4096];   // 128 rows x 32 cols per buffer
  const int t = threadIdx.x;

  const int nbm = gridDim.x;
  const int nwg = nbm * gridDim.y;
  int wid = blockIdx.x + nbm * blockIdx.y;
  wid = (wid & 7) * (nwg >> 3) + (wid >> 3);
  const int bm = wid % nbm, bn = wid / nbm;

  const int w = t >> 6, l = t & 63;
  const int wm = w >> 1, wn = w & 1;          // 4m x 2n waves
  const int l15 = l & 15, l4 = l >> 4;

  const int colblk = ((t & 3) ^ ((t >> 3) & 3)) * 8;
  const bf16* gA = A  + (size_t)(bm * 256 + (t >> 2)) * lda + colblk;
  const bf16* gB = BT + (size_t)(bn * 128 + (t >> 2)) * ldb + colblk;
  const int dst = w * 512;

  auto stage = [&](int kt, int buf) {
    const int k0 = kt * 32;
    gload16(gA + k0, &As[buf][dst]);                             // A rows 0..127
    gload16(gA + (size_t)128 * lda + k0, &As[buf][4096 + dst]);  // A rows 128..255
    gload16(gB + k0, &Bs[buf][dst]);                             // B rows 0..127
  };

  const int rd = (l4 ^ ((l15 >> 1) & 3)) * 8;
  const int arow = wm * 64 + l15;
  const int brow = wn * 64 + l15;

  f32x4 acc[4][4];
  #pragma unroll
  for (int m = 0; m < 4; ++m)
    #pragma unroll
    for (int n = 0; n < 4; ++n)
      acc[m][n] = (f32x4){0.f, 0.f, 0.f, 0.f};

  const int NT = K >> 5;
  stage(0, 0);
  stage(1, 1);

  int buf = 0;
  for (int kt = 0; kt < NT; ++kt) {
    if (kt + 1 < NT) asm volatile("s_waitcnt vmcnt(3)" ::: "memory");
    else             asm volatile("s_waitcnt vmcnt(0)" ::: "memory");
    __builtin_amdgcn_s_barrier();            // single barrier per K-tile
    __builtin_amdgcn_sched_barrier(0);

    int nb = buf + 2; if (nb >= 3) nb -= 3;

    bf16x8 af[4], bfr[4];
    #pragma unroll
    for (int n = 0; n < 4; ++n)
      bfr[n] = *(const bf16x8*)&Bs[buf][(brow + n * 16) * 32 + rd];
    #pragma unroll
    for (int m = 0; m < 4; ++m)
      af[m] = *(const bf16x8*)&As[buf][(arow + m * 16) * 32 + rd];
    if (kt + 2 < NT) stage(kt + 2, nb);
    asm volatile("s_waitcnt lgkmcnt(0)" ::: "memory");
    __builtin_amdgcn_sched_barrier(0);

    __builtin_amdgcn_s_setprio(1);
    #pragma unroll
    for (int m = 0; m < 4; ++m)
      #pragma unroll
      for (int n = 0; n < 4; ++n)
        acc[m][n] = mfma16(af[m], bfr[n], acc[m][n]);
    __builtin_amdgcn_s_setprio(0);
    __builtin_amdgcn_sched_barrier(0);

    if (++buf >= 3) buf = 0;
  }

  #pragma unroll
  for (int n = 0; n < 4; ++n) {
    const int col = bn * 128 + wn * 64 + n * 16 + l15;
    const float bv = bias[col];
    #pragma unroll
    for (int m = 0; m < 4; ++m) {
      const int row = bm * 256 + wm * 64 + m * 16 + l4 * 4;
      #pragma unroll
      for (int r = 0; r < 4; ++r)
        C[(size_t)(row + r) * ldc + col] = acc[m][n][r] + bv;
    }
  }
}

// ---------------- flash attention (8 waves x 16 q-rows, LDS XOR-swizzled) ----
// grid: (S/128, B*H), block 512. Fixup for leading-pad rows fused in epilogue.
__global__ __launch_bounds__(512) void attn_kernel(
    const bf16* __restrict__ qkv, const bf16* __restrict__ vT,
    const int* __restrict__ tokens, bf16* __restrict__ ctx)
{
  __shared__ bf16 Ks[128 * 64];
  __shared__ bf16 VTs[64 * 128];
  __shared__ bf16 Ps[128 * 128];

  const int qt = blockIdx.x;
  const int bh = blockIdx.y;
  const int b = bh >> 4, h = bh & 15;
  const int t = threadIdx.x, w = t >> 6, l = t & 63;
  const int l15 = l & 15, l4 = l >> 4;
  const int q0 = qt * 128;

  bf16x8 aq[2];
  #pragma unroll
  for (int ks = 0; ks < 2; ++ks)
    aq[ks] = *(const bf16x8*)(qkv +
        (size_t)(b * 1024 + q0 + w * 16 + l15) * 3072 +
        h * 64 + ks * 32 + l4 * 8);

  f32x4 o[4];
  float m_run[4], l_run[4];
  #pragma unroll
  for (int r = 0; r < 4; ++r) { m_run[r] = -1e30f; l_run[r] = 0.f; }
  #pragma unroll
  for (int nn = 0; nn < 4; ++nn)
    o[nn] = (f32x4){0.f, 0.f, 0.f, 0.f};

  const bf16* kb = qkv + (size_t)(b * 1024) * 3072 + 1024 + h * 64;
  const bf16* vb = vT + (size_t)(bh * 64) * 1024;
  const int* tb = tokens + b * 1024;

  const int kSrcCol = ((t & 7) ^ ((t >> 3) & 7)) * 8;     // K key: row&7
  const int vSrcCol = ((t & 15) ^ ((t >> 4) & 15)) * 8;   // V key: row&15

  for (int jt = 0; jt <= qt; ++jt) {
    const int j0 = jt * 128;
    __syncthreads();
    #pragma unroll
    for (int i = 0; i < 2; ++i)
      gload16(kb + (size_t)(j0 + i * 64 + (t >> 3)) * 3072 + kSrcCol,
              Ks + i * 4096 + w * 512);
    #pragma unroll
    for (int i = 0; i < 2; ++i)
      gload16(vb + (size_t)(i * 32 + (t >> 4)) * 1024 + j0 + vSrcCol,
              VTs + i * 4096 + w * 512);
    __syncthreads();

    f32x4 s[8];
    #pragma unroll
    for (int n = 0; n < 8; ++n)
      s[n] = (f32x4){0.f, 0.f, 0.f, 0.f};
    #pragma unroll
    for (int ks = 0; ks < 2; ++ks) {
      #pragma unroll
      for (int n = 0; n < 8; ++n) {
        const bf16x8 bk = *(const bf16x8*)
            &Ks[(n * 16 + l15) * 64 + ((ks * 32 + l4 * 8) ^ ((l15 & 7) * 8))];
        s[n] = mfma16(aq[ks], bk, s[n]);
      }
    }

    float padv[8];
    #pragma unroll
    for (int n = 0; n < 8; ++n)
      padv[n] = (tb[j0 + n * 16 + l15] == 0) ? 1.f : 0.f;

    #pragma unroll
    for (int r = 0; r < 4; ++r) {
      const int rloc = l4 * 4 + r;
      const int qrow = q0 + w * 16 + rloc;
      float vals[8];
      float mx = -1e30f;
      #pragma unroll
      for (int n = 0; n < 8; ++n) {
        const int jg = j0 + n * 16 + l15;
        float v = s[n][r] * 0.125f;
        if (jg > qrow || padv[n] != 0.f) v = -1e9f;
        vals[n] = v;
        mx = fmaxf(mx, v);
      }
      #pragma unroll
      for (int d = 1; d < 16; d <<= 1) mx = fmaxf(mx, __shfl_xor(mx, d));
      const float newm = fmaxf(m_run[r], mx);
      const float sc = __expf(m_run[r] - newm);
      m_run[r] = newm;
      float rs = 0.f;
      #pragma unroll
      for (int n = 0; n < 8; ++n) {
        const float pv = __expf(vals[n] - newm);
        vals[n] = pv;
        rs += pv;
      }
      #pragma unroll
      for (int d = 1; d < 16; d <<= 1) rs += __shfl_xor(rs, d);
      l_run[r] = l_run[r] * sc + rs;
      #pragma unroll
      for (int nn = 0; nn < 4; ++nn) o[nn][r] = o[nn][r] * sc;
      #pragma unroll
      for (int n = 0; n < 8; ++n)
        Ps[(w * 16 + rloc) * 128 + ((n * 16 + l15) ^ (rloc * 8))] = f2b(vals[n]);
    }
    asm volatile("s_waitcnt lgkmcnt(0)" ::: "memory");

    #pragma unroll
    for (int ks = 0; ks < 4; ++ks) {
      const bf16x8 ap = *(const bf16x8*)
          &Ps[(w * 16 + l15) * 128 + ((ks * 32 + l4 * 8) ^ (l15 * 8))];
      #pragma unroll
      for (int nn = 0; nn < 4; ++nn) {
        const bf16x8 bv = *(const bf16x8*)
            &VTs[(nn * 16 + l15) * 128 + ((ks * 32 + l4 * 8) ^ (l15 * 8))];
        o[nn] = mfma16(ap, bv, o[nn]);
      }
    }
  }

  #pragma unroll
  for (int r = 0; r < 4; ++r) {
    const float inv = 1.0f / l_run[r];
    const int qrow = q0 + w * 16 + l4 * 4 + r;
    #pragma unroll
    for (int nn = 0; nn < 4; ++nn)
      ctx[(size_t)(b * 1024 + qrow) * 1024 + h * 64 + nn * 16 + l15] =
          f2b(o[nn][r] * inv);
  }

  // fused fixup: rows < P0 (leading pads) -> ctx = mean over all S of V.
  int loc = 1024;
  #pragma unroll 4
  for (int j = 0; j < 16; ++j) {
    const int idx = l * 16 + j;
    if (tb[idx] != 0) { loc = idx; break; }
  }
  #pragma unroll
  for (int d = 1; d < 64; d <<= 1) {
    const int o2 = __shfl_xor(loc, d);
    loc = (o2 < loc) ? o2 : loc;
  }
  const int P0 = loc;
  if (P0 > q0) {
    __syncthreads();
    const int rbeg = q0 + w * 16;
    if (P0 > rbeg) {
      const bf16* vrow = vb + (size_t)l * 1024;
      float sum = 0.f;
      for (int sIdx = 0; sIdx < 1024; sIdx += 4) {
        const ushort4 pv = *(const ushort4*)&vrow[sIdx];
        sum += u2f(pv.x) + u2f(pv.y) + u2f(pv.z) + u2f(pv.w);
      }
      const bf16 mv = f2b(sum * (1.0f / 1024.0f));
      const int rend = (P0 < rbeg + 16) ? P0 : (rbeg + 16);
      for (int q = rbeg; q < rend; ++q)
        ctx[(size_t)(b * 1024 + q) * 1024 + h * 64 + l] = mv;
    }
  }
}

// ---------------- host ----------------
extern "C" void kernel_launch(void* const* d_in, const int* in_sizes, int n_in,
                              void* d_out, int out_size, void* d_ws, size_t ws_size,
                              hipStream_t stream)
{
  (void)in_sizes; (void)n_in; (void)out_size;
  const int*   tokens = (const int*)d_in[0];
  const float* emb  = (const float*)d_in[1];
  const float* pe   = (const float*)d_in[2];
  const float* Wq   = (const float*)d_in[3];
  const float* Wk   = (const float*)d_in[4];
  const float* Wv   = (const float*)d_in[5];
  const float* Wo   = (const float*)d_in[6];
  const float* bo   = (const float*)d_in[7];
  const float* g1   = (const float*)d_in[8];
  const float* be1  = (const float*)d_in[9];
  const float* g2   = (const float*)d_in[10];
  const float* be2  = (const float*)d_in[11];
  const float* W1   = (const float*)d_in[12];
  const float* b1   = (const float*)d_in[13];
  const float* W2   = (const float*)d_in[14];
  const float* b2   = (const float*)d_in[15];
  const float* gf   = (const float*)d_in[16];
  const float* bff  = (const float*)d_in[17];
  const float* Wout = (const float*)d_in[18];
  const float* bout = (const float*)d_in[19];
  float* out = (float*)d_out;

  char* p = (char*)d_ws;
  auto alloc = [&](size_t bytes) {
    char* q = p;
    p += (bytes + 255) & ~(size_t)255;
    return q;
  };
  float* x    = (float*)alloc((size_t)2048 * 1024 * 4);
  bf16* Pp    = (bf16*)alloc((size_t)4 * 2048 * 1024 * 2);  // bf16 K-slice partials
  bf16* h     = (bf16*)alloc((size_t)2048 * 1024 * 2);
  bf16* qkv   = (bf16*)alloc((size_t)2048 * 3072 * 2);
  bf16* vT    = (bf16*)alloc((size_t)2048 * 1024 * 2);
  bf16* ctx   = (bf16*)alloc((size_t)2048 * 1024 * 2);
  bf16* ff    = (bf16*)alloc((size_t)2048 * 4096 * 2);
  bf16* WoutT = (bf16*)alloc((size_t)32000 * 1024 * 2);

  const size_t DD = (size_t)1024 * 1024;
  const size_t DF = (size_t)1024 * 4096;

  const size_t perLayerW = (3 * DD + DD + DF + DF) * 2;
  const size_t used = (size_t)(p - (char*)d_ws);
  const bool fullprep = ws_size >= used + 6 * perLayerW + 8192;
  const int NL = fullprep ? 6 : 1;
  bf16* WqkvT = (bf16*)alloc((size_t)NL * 3 * DD * 2);
  bf16* WoT   = (bf16*)alloc((size_t)NL * DD * 2);
  bf16* W1T   = (bf16*)alloc((size_t)NL * DF * 2);
  bf16* W2T   = (bf16*)alloc((size_t)NL * DF * 2);

  if (fullprep)
    prep_all_kernel<<<6 * 3072 + 8000, 256, 0, stream>>>(
        Wq, Wk, Wv, Wo, W1, W2, Wout, WqkvT, WoT, W1T, W2T, WoutT);

  // fused embed + ln1(layer 0)
  embed_ln_kernel<<<2048, 256, 0, stream>>>(tokens, emb, pe, g1, be1, x, h);

  for (int l = 0; l < 6; ++l) {
    const bf16* wqkvt; const bf16* wot; const bf16* w1t; const bf16* w2t;
    if (fullprep) {
      wqkvt = WqkvT + (size_t)l * 3 * DD;
      wot   = WoT   + (size_t)l * DD;
      w1t   = W1T   + (size_t)l * DF;
      w2t   = W2T   + (size_t)l * DF;
    } else {
      prep_layer_kernel<<<3072, 256, 0, stream>>>(
          Wq + l * DD, Wk + l * DD, Wv + l * DD, Wo + l * DD,
          W1 + l * DF, W2 + l * DF, WqkvT, WoT, W1T, W2T);
      wqkvt = WqkvT; wot = WoT; w1t = W1T; w2t = W2T;
    }

    // ln1 for layers >0: fold previous FFN2 partials (np=4)
    if (l > 0)
      ln_res_kernel<<<2048, 256, 0, stream>>>(
          x, Pp, 4, b2 + (l - 1) * 1024, g1 + l * 1024, be1 + l * 1024, h);

    // QKV: M=2048 N=3072 K=1024 -> 384 blocks; fused V-transpose epilogue
    gemm_pl<4, 0><<<dim3(16, 24, 1), 256, 0, stream>>>(
        h, 1024, wqkvt, 1024, qkv, 3072, (const float*)nullptr, vT, 1024);
    attn_kernel<<<dim3(8, 32), 512, 0, stream>>>(qkv, vT, tokens, ctx);
    // Wo: M=2048 N=1024 K=1024, splitK4 -> 512 blocks, bf16 partials
    gemm_pl<3, 0><<<dim3(16, 8, 4), 256, 0, stream>>>(
        ctx, 1024, wot, 1024, Pp, 1024, (const float*)nullptr,
        (bf16*)nullptr, 256);
    // ln2: x += sum(P0..3) + bo; h = LN(x)
    ln_res_kernel<<<2048, 256, 0, stream>>>(
        x, Pp, 4, bo + l * 1024, g2 + l * 1024, be2 + l * 1024, h);
    // FFN1: M=2048 N=4096 K=1024 -> 512 blocks
    gemm_pl<2, 0><<<dim3(16, 32, 1), 256, 0, stream>>>(
        h, 1024, w1t, 1024, ff, 4096, b1 + l * 4096, (bf16*)nullptr, 1024);
    // FFN2: M=2048 N=1024 K=4096, splitK4 -> 512 blocks, bf16 partials
    gemm_pl<3, 0><<<dim3(16, 8, 4), 256, 0, stream>>>(
        ff, 4096, w2t, 4096, Pp, 1024, (const float*)nullptr,
        (bf16*)nullptr, 1024);
  }

  // final LN folds layer-5 FFN2 partials
  ln_res_kernel<<<2048, 256, 0, stream>>>(x, Pp, 4, b2 + 5 * 1024, gf, bff, h);
  if (!fullprep)
    transpose_cast_kernel<<<dim3(500, 16), 256, 0, stream>>>(Wout, WoutT, 32000, 1024);
  // logits: M=2048 N=32000 K=1024 -> 256x128 single-barrier ring, 2000 blocks
  gemm256<<<dim3(8, 250), 512, 0, stream>>>(
      h, 1024, WoutT, 1024, out, 32000, bout, 1024);
}

// Round 15
// 1208.974 us; speedup vs baseline: 1.0285x; 1.0285x over previous
//
#include <hip/hip_runtime.h>
#include <hip/hip_bf16.h>
#include <stdint.h>

typedef __hip_bfloat16 bf16;
typedef __attribute__((ext_vector_type(8))) short bf16x8;
typedef __attribute__((ext_vector_type(4))) float f32x4;

#define DEV static __device__ __forceinline__

DEV float b2f(bf16 v) { return __bfloat162float(v); }
DEV bf16  f2b(float v) { return __float2bfloat16(v); }

DEV float u2f(unsigned short u) {
  unsigned int x = (unsigned int)u << 16;
  float f;
  __builtin_memcpy(&f, &x, 4);
  return f;
}

DEV unsigned short f2u(float v) {
  bf16 b = f2b(v);
  unsigned short u;
  __builtin_memcpy(&u, &b, 2);
  return u;
}

DEV void gload16(const void* g, void* l) {
  __builtin_amdgcn_global_load_lds(
      (__attribute__((address_space(1))) void*)(void*)g,
      (__attribute__((address_space(3))) void*)l, 16, 0, 0);
}

DEV f32x4 mfma16(bf16x8 a, bf16x8 b, f32x4 c) {
  return __builtin_amdgcn_mfma_f32_16x16x32_bf16(a, b, c, 0, 0, 0);
}

// -------- fused embed + layernorm (layer 0): x = emb[tok]*32+pe; h = LN(x) ----
__global__ __launch_bounds__(256) void embed_ln_kernel(
    const int* __restrict__ tok, const float* __restrict__ emb,
    const float* __restrict__ pe, const float* __restrict__ g,
    const float* __restrict__ be, float* __restrict__ x, bf16* __restrict__ h)
{
  const int r = blockIdx.x, t = threadIdx.x;
  const int s = r & 1023;
  const int tk = tok[r];
  const float4 e  = ((const float4*)(emb + (size_t)tk * 1024))[t];
  const float4 pp = ((const float4*)(pe + (size_t)s * 1024))[t];
  float4 v;
  v.x = e.x * 32.0f + pp.x;
  v.y = e.y * 32.0f + pp.y;
  v.z = e.z * 32.0f + pp.z;
  v.w = e.w * 32.0f + pp.w;

  float sm  = v.x + v.y + v.z + v.w;
  float sq = v.x * v.x + v.y * v.y + v.z * v.z + v.w * v.w;
  #pragma unroll
  for (int d = 1; d < 64; d <<= 1) {
    sm += __shfl_xor(sm, d);
    sq += __shfl_xor(sq, d);
  }
  __shared__ float red[8];
  const int w = t >> 6, l = t & 63;
  if (l == 0) { red[w] = sm; red[4 + w] = sq; }
  __syncthreads();
  sm = red[0] + red[1] + red[2] + red[3];
  sq = red[4] + red[5] + red[6] + red[7];
  const float mean = sm * (1.0f / 1024.0f);
  const float var  = sq * (1.0f / 1024.0f) - mean * mean;
  const float inv  = 1.0f / sqrtf(var + 1e-5f);

  ((float4*)(x + (size_t)r * 1024))[t] = v;
  bf16* hp = h + (size_t)r * 1024 + t * 4;
  const float* gp = g + t * 4;
  const float* bp = be + t * 4;
  const float vv[4] = {v.x, v.y, v.z, v.w};
  #pragma unroll
  for (int j = 0; j < 4; ++j)
    hp[j] = f2b((vv[j] - mean) * inv * gp[j] + bp[j]);
}

// -- fused residual + layernorm: x += sum(bf16 P[0..np)) + bias; h = LN(x)*g+be
__global__ __launch_bounds__(256) void ln_res_kernel(
    float* __restrict__ x, const bf16* __restrict__ P, int np,
    const float* __restrict__ bias, const float* __restrict__ g,
    const float* __restrict__ be, bf16* __restrict__ h)
{
  const int r = blockIdx.x, t = threadIdx.x;
  float4 v = ((const float4*)(x + (size_t)r * 1024))[t];
  for (int i = 0; i < np; ++i) {
    const ushort4 pv = ((const ushort4*)(P + ((size_t)i * 2048 + r) * 1024))[t];
    v.x += u2f(pv.x); v.y += u2f(pv.y); v.z += u2f(pv.z); v.w += u2f(pv.w);
  }
  const float4 bv = ((const float4*)bias)[t];
  v.x += bv.x; v.y += bv.y; v.z += bv.z; v.w += bv.w;

  float s  = v.x + v.y + v.z + v.w;
  float sq = v.x * v.x + v.y * v.y + v.z * v.z + v.w * v.w;
  #pragma unroll
  for (int d = 1; d < 64; d <<= 1) {
    s  += __shfl_xor(s, d);
    sq += __shfl_xor(sq, d);
  }
  __shared__ float red[8];
  const int w = t >> 6, l = t & 63;
  if (l == 0) { red[w] = s; red[4 + w] = sq; }
  __syncthreads();
  s  = red[0] + red[1] + red[2] + red[3];
  sq = red[4] + red[5] + red[6] + red[7];
  const float mean = s * (1.0f / 1024.0f);
  const float var  = sq * (1.0f / 1024.0f) - mean * mean;
  const float inv  = 1.0f / sqrtf(var + 1e-5f);

  ((float4*)(x + (size_t)r * 1024))[t] = v;
  bf16* hp = h + (size_t)r * 1024 + t * 4;
  const float* gp = g + t * 4;
  const float* bp = be + t * 4;
  const float vv[4] = {v.x, v.y, v.z, v.w};
  #pragma unroll
  for (int j = 0; j < 4; ++j)
    hp[j] = f2b((vv[j] - mean) * inv * gp[j] + bp[j]);
}

// ------------- 64x64 transpose+cast tile body -------------
DEV void transpose_tile(const float* __restrict__ in, bf16* __restrict__ out,
                        int ldin, int ldout, int r0, int c0, int t)
{
  __shared__ bf16 tile[64][64];
  #pragma unroll
  for (int i = 0; i < 4; ++i) {
    const int r = i * 16 + (t >> 4), c = (t & 15) * 4;
    const float4 v = *(const float4*)&in[(size_t)(r0 + r) * ldin + c0 + c];
    tile[r][c + 0] = f2b(v.x);
    tile[r][c + 1] = f2b(v.y);
    tile[r][c + 2] = f2b(v.z);
    tile[r][c + 3] = f2b(v.w);
  }
  __syncthreads();
  #pragma unroll
  for (int i = 0; i < 2; ++i) {
    const int oc = i * 32 + (t >> 3);
    const int rr = (t & 7) * 8;
    unsigned short tmp[8] __attribute__((aligned(16)));
    #pragma unroll
    for (int j = 0; j < 8; ++j)
      tmp[j] = ((const unsigned short*)tile)[(rr + j) * 64 + oc];
    *(uint4*)&out[(size_t)(c0 + oc) * ldout + r0 + rr] = *(const uint4*)tmp;
  }
}

// generic single-matrix transpose+cast (Wout, launched just before logits
// so WoutT is L3-hot when gemm256 consumes it — round-14 lesson)
__global__ __launch_bounds__(256) void transpose_cast_kernel(
    const float* __restrict__ in, bf16* __restrict__ out, int ldin, int ldout)
{
  transpose_tile(in, out, ldin, ldout, blockIdx.y * 64, blockIdx.x * 64, threadIdx.x);
}

// dispatch one 64x64 tile of the per-layer weight set (3072 tiles/layer)
DEV void prep_dispatch(int wid,
    const float* Wq, const float* Wk, const float* Wv, const float* Wo,
    const float* W1, const float* W2,
    bf16* WqkvT, bf16* WoT, bf16* W1T, bf16* W2T, int t)
{
  const float* src; bf16* dst; int ldin, ldout, tx, ty;
  if (wid < 768) {
    const int m = wid >> 8, tt = wid & 255;
    src = (m == 0) ? Wq : (m == 1) ? Wk : Wv;
    dst = WqkvT + (size_t)m * 1024 * 1024;
    ldin = 1024; ldout = 1024; tx = tt & 15; ty = tt >> 4;
  } else if (wid < 1024) {
    const int tt = wid - 768;
    src = Wo; dst = WoT; ldin = 1024; ldout = 1024; tx = tt & 15; ty = tt >> 4;
  } else if (wid < 2048) {
    const int tt = wid - 1024;
    src = W1; dst = W1T; ldin = 4096; ldout = 1024; tx = tt & 63; ty = tt >> 6;
  } else {
    const int tt = wid - 2048;
    src = W2; dst = W2T; ldin = 1024; ldout = 4096; tx = tt & 15; ty = tt >> 4;
  }
  transpose_tile(src, dst, ldin, ldout, ty * 64, tx * 64, t);
}

// per-layer weight prep (fallback path)
__global__ __launch_bounds__(256) void prep_layer_kernel(
    const float* __restrict__ Wq, const float* __restrict__ Wk,
    const float* __restrict__ Wv, const float* __restrict__ Wo,
    const float* __restrict__ W1, const float* __restrict__ W2,
    bf16* __restrict__ WqkvT, bf16* __restrict__ WoT,
    bf16* __restrict__ W1T, bf16* __restrict__ W2T)
{
  prep_dispatch(blockIdx.x, Wq, Wk, Wv, Wo, W1, W2,
                WqkvT, WoT, W1T, W2T, threadIdx.x);
}

// all-layers weight prep: 6*3072 blocks (Wout handled separately pre-logits)
__global__ __launch_bounds__(256) void prep_all_kernel(
    const float* __restrict__ Wq, const float* __restrict__ Wk,
    const float* __restrict__ Wv, const float* __restrict__ Wo,
    const float* __restrict__ W1, const float* __restrict__ W2,
    bf16* __restrict__ WqkvT, bf16* __restrict__ WoT,
    bf16* __restrict__ W1T, bf16* __restrict__ W2T)
{
  const size_t DD = (size_t)1024 * 1024, DF = (size_t)1024 * 4096;
  const int layer = blockIdx.x / 3072;
  const int wid = blockIdx.x - layer * 3072;
  prep_dispatch(wid,
      Wq + layer * DD, Wk + layer * DD, Wv + layer * DD, Wo + layer * DD,
      W1 + layer * DF, W2 + layer * DF,
      WqkvT + layer * 3 * DD, WoT + layer * DD,
      W1T + layer * DF, W2T + layer * DF, threadIdx.x);
}

// ------------- pipelined GEMM: C(MxN) = A(MxK,row) * BT(NxK,row)^T -------------
// BM=BN=128, BK=32; 3-buffer single-barrier ring (48 KB LDS -> 3 blocks/CU),
// counted vmcnt(4) (T4), verified conflict-free T2 XOR swizzle.
// EPI: 0 = bf16 store; 1 = +bias f32 store; 2 = gelu(acc+bias) bf16;
//      3 = bf16 K-slice partial store P[z][M][N]; 4 = QKV fused: cols<2048 ->
//          qkv bf16, cols>=2048 -> vT[(b*1024+hk)*1024+s] transposed write
// grid: (M/128, N/128, KSLICES), block 256 (4 waves), K-slice length ksl
template<int EPI, int SWZ>
__global__ __launch_bounds__(256, 3) void gemm_pl(
    const bf16* __restrict__ A, int lda,
    const bf16* __restrict__ BT, int ldb,
    void* __restrict__ Cp, int ldc,
    const float* __restrict__ bias,
    bf16* __restrict__ vTp,
    int ksl)
{
  __shared__ bf16 As[3][4096];
  __shared__ bf16 Bs[3][4096];
  const int t = threadIdx.x;

  int bm, bn;
  if constexpr (SWZ) {
    const int nbm = gridDim.x;
    const int nwg = nbm * gridDim.y;
    int wid = blockIdx.x + nbm * blockIdx.y;
    wid = (wid & 7) * (nwg >> 3) + (wid >> 3);
    bm = wid % nbm; bn = wid / nbm;
  } else {
    bm = blockIdx.x; bn = blockIdx.y;
  }

  const int w = t >> 6, l = t & 63;
  const int wr = (w >> 1) * 64, wc = (w & 1) * 64;
  const int l15 = l & 15, l4 = l >> 4;
  const int kbeg = blockIdx.z * ksl;
  const int NT = ksl >> 5;

  const int colblk = (((t & 3) ^ ((t >> 3) & 3))) * 8;
  const bf16* gA = A  + (size_t)(bm * 128 + (t >> 2)) * lda + colblk + kbeg;
  const bf16* gB = BT + (size_t)(bn * 128 + (t >> 2)) * ldb + colblk + kbeg;
  const int dst = w * 512;

  auto stage = [&](int tile, int buf) {
    const int k0 = tile * 32;
    gload16(gA + k0, &As[buf][dst]);
    gload16(gA + (size_t)64 * lda + k0, &As[buf][2048 + dst]);
    gload16(gB + k0, &Bs[buf][dst]);
    gload16(gB + (size_t)64 * ldb + k0, &Bs[buf][2048 + dst]);
  };

  f32x4 acc[4][4];
  #pragma unroll
  for (int m = 0; m < 4; ++m)
    #pragma unroll
    for (int n = 0; n < 4; ++n)
      acc[m][n] = (f32x4){0.f, 0.f, 0.f, 0.f};

  stage(0, 0);
  stage(1, 1);

  const int rdcol = ((l4 ^ ((l15 >> 1) & 3))) * 8;

  int buf = 0;
  for (int kt = 0; kt < NT; ++kt) {
    if (kt + 1 < NT) asm volatile("s_waitcnt vmcnt(4)" ::: "memory");
    else             asm volatile("s_waitcnt vmcnt(0)" ::: "memory");
    __builtin_amdgcn_s_barrier();
    __builtin_amdgcn_sched_barrier(0);

    int nb = buf + 2; if (nb >= 3) nb -= 3;

    bf16x8 af[4], bfr[4];
    #pragma unroll
    for (int m = 0; m < 4; ++m)
      af[m] = *(const bf16x8*)&As[buf][(wr + m * 16 + l15) * 32 + rdcol];
    #pragma unroll
    for (int n = 0; n < 4; ++n)
      bfr[n] = *(const bf16x8*)&Bs[buf][(wc + n * 16 + l15) * 32 + rdcol];
    if (kt + 2 < NT) stage(kt + 2, nb);
    asm volatile("s_waitcnt lgkmcnt(0)" ::: "memory");
    __builtin_amdgcn_sched_barrier(0);

    __builtin_amdgcn_s_setprio(1);
    #pragma unroll
    for (int m = 0; m < 4; ++m)
      #pragma unroll
      for (int n = 0; n < 4; ++n)
        acc[m][n] = mfma16(af[m], bfr[n], acc[m][n]);
    __builtin_amdgcn_s_setprio(0);
    __builtin_amdgcn_sched_barrier(0);

    if (++buf >= 3) buf = 0;
  }

  const int crow = bm * 128 + wr, ccol = bn * 128 + wc;
  #pragma unroll
  for (int n = 0; n < 4; ++n) {
    const int col = ccol + n * 16 + l15;
    float bv = 0.f;
    if (EPI == 1 || EPI == 2) bv = bias[col];
    #pragma unroll
    for (int m = 0; m < 4; ++m) {
      const int row = crow + m * 16 + l4 * 4;
      if (EPI == 4 && ccol >= 2048) {
        const int b = row >> 10, s = row & 1023;
        const int hk = col - 2048;
        ushort4 pk;
        pk.x = f2u(acc[m][n][0]); pk.y = f2u(acc[m][n][1]);
        pk.z = f2u(acc[m][n][2]); pk.w = f2u(acc[m][n][3]);
        *(ushort4*)&vTp[((size_t)b * 1024 + hk) * 1024 + s] = pk;
        continue;
      }
      #pragma unroll
      for (int r = 0; r < 4; ++r) {
        const float v = acc[m][n][r];
        if (EPI == 0 || EPI == 4) {
          ((bf16*)Cp)[(size_t)(row + r) * ldc + col] = f2b(v);
        } else if (EPI == 1) {
          ((float*)Cp)[(size_t)(row + r) * ldc + col] = v + bv;
        } else if (EPI == 2) {
          const float u = v + bv;
          const float gel = 0.5f * u * (1.0f + erff(u * 0.70710678118654752f));
          ((bf16*)Cp)[(size_t)(row + r) * ldc + col] = f2b(gel);
        } else {
          const int M = gridDim.x * 128;
          ((bf16*)Cp)[((size_t)blockIdx.z * M + row + r) * ldc + col] = f2b(v);
        }
      }
    }
  }
}

// ------------- 256x128 8-wave single-barrier GEMM (logits; round-12 best) ----
__global__ __launch_bounds__(512, 4) void gemm256(
    const bf16* __restrict__ A, int lda,
    const bf16* __restrict__ BT, int ldb,
    float* __restrict__ C, int ldc,
    const float* __restrict__ bias, int K)
{
  __shared__ bf16 As[3][8192];
  __shared__ bf16 Bs[3][4096];
  const int t = threadIdx.x;

  const int nbm = gridDim.x;
  const int nwg = nbm * gridDim.y;
  int wid = blockIdx.x + nbm * blockIdx.y;
  wid = (wid & 7) * (nwg >> 3) + (wid >> 3);
  const int bm = wid % nbm, bn = wid / nbm;

  const int w = t >> 6, l = t & 63;
  const int wm = w >> 1, wn = w & 1;
  const int l15 = l & 15, l4 = l >> 4;

  const int colblk = ((t & 3) ^ ((t >> 3) & 3)) * 8;
  const bf16* gA = A  + (size_t)(bm * 256 + (t >> 2)) * lda + colblk;
  const bf16* gB = BT + (size_t)(bn * 128 + (t >> 2)) * ldb + colblk;
  const int dst = w * 512;

  auto stage = [&](int kt, int buf) {
    const int k0 = kt * 32;
    gload16(gA + k0, &As[buf][dst]);
    gload16(gA + (size_t)128 * lda + k0, &As[buf][4096 + dst]);
    gload16(gB + k0, &Bs[buf][dst]);
  };

  const int rd = (l4 ^ ((l15 >> 1) & 3)) * 8;
  const int arow = wm * 64 + l15;
  const int brow = wn * 64 + l15;

  f32x4 acc[4][4];
  #pragma unroll
  for (int m = 0; m < 4; ++m)
    #pragma unroll
    for (int n = 0; n < 4; ++n)
      acc[m][n] = (f32x4){0.f, 0.f, 0.f, 0.f};

  const int NT = K >> 5;
  stage(0, 0);
  stage(1, 1);

  int buf = 0;
  for (int kt = 0; kt < NT; ++kt) {
    if (kt + 1 < NT) asm volatile("s_waitcnt vmcnt(3)" ::: "memory");
    else             asm volatile("s_waitcnt vmcnt(0)" ::: "memory");
    __builtin_amdgcn_s_barrier();
    __builtin_amdgcn_sched_barrier(0);

    int nb = buf + 2; if (nb >= 3) nb -= 3;

    bf16x8 af[4], bfr[4];
    #pragma unroll
    for (int n = 0; n < 4; ++n)
      bfr[n] = *(const bf16x8*)&Bs[buf][(brow + n * 16) * 32 + rd];
    #pragma unroll
    for (int m = 0; m < 4; ++m)
      af[m] = *(const bf16x8*)&As[buf][(arow + m * 16) * 32 + rd];
    if (kt + 2 < NT) stage(kt + 2, nb);
    asm volatile("s_waitcnt lgkmcnt(0)" ::: "memory");
    __builtin_amdgcn_sched_barrier(0);

    __builtin_amdgcn_s_setprio(1);
    #pragma unroll
    for (int m = 0; m < 4; ++m)
      #pragma unroll
      for (int n = 0; n < 4; ++n)
        acc[m][n] = mfma16(af[m], bfr[n], acc[m][n]);
    __builtin_amdgcn_s_setprio(0);
    __builtin_amdgcn_sched_barrier(0);

    if (++buf >= 3) buf = 0;
  }

  #pragma unroll
  for (int n = 0; n < 4; ++n) {
    const int col = bn * 128 + wn * 64 + n * 16 + l15;
    const float bv = bias[col];
    #pragma unroll
    for (int m = 0; m < 4; ++m) {
      const int row = bm * 256 + wm * 64 + m * 16 + l4 * 4;
      #pragma unroll
      for (int r = 0; r < 4; ++r)
        C[(size_t)(row + r) * ldc + col] = acc[m][n][r] + bv;
    }
  }
}

// ---------------- flash attention (8 waves x 16 q-rows, LDS XOR-swizzled) ----
__global__ __launch_bounds__(512) void attn_kernel(
    const bf16* __restrict__ qkv, const bf16* __restrict__ vT,
    const int* __restrict__ tokens, bf16* __restrict__ ctx)
{
  __shared__ bf16 Ks[128 * 64];
  __shared__ bf16 VTs[64 * 128];
  __shared__ bf16 Ps[128 * 128];

  const int qt = blockIdx.x;
  const int bh = blockIdx.y;
  const int b = bh >> 4, h = bh & 15;
  const int t = threadIdx.x, w = t >> 6, l = t & 63;
  const int l15 = l & 15, l4 = l >> 4;
  const int q0 = qt * 128;

  bf16x8 aq[2];
  #pragma unroll
  for (int ks = 0; ks < 2; ++ks)
    aq[ks] = *(const bf16x8*)(qkv +
        (size_t)(b * 1024 + q0 + w * 16 + l15) * 3072 +
        h * 64 + ks * 32 + l4 * 8);

  f32x4 o[4];
  float m_run[4], l_run[4];
  #pragma unroll
  for (int r = 0; r < 4; ++r) { m_run[r] = -1e30f; l_run[r] = 0.f; }
  #pragma unroll
  for (int nn = 0; nn < 4; ++nn)
    o[nn] = (f32x4){0.f, 0.f, 0.f, 0.f};

  const bf16* kb = qkv + (size_t)(b * 1024) * 3072 + 1024 + h * 64;
  const bf16* vb = vT + (size_t)(bh * 64) * 1024;
  const int* tb = tokens + b * 1024;

  const int kSrcCol = ((t & 7) ^ ((t >> 3) & 7)) * 8;
  const int vSrcCol = ((t & 15) ^ ((t >> 4) & 15)) * 8;

  for (int jt = 0; jt <= qt; ++jt) {
    const int j0 = jt * 128;
    __syncthreads();
    #pragma unroll
    for (int i = 0; i < 2; ++i)
      gload16(kb + (size_t)(j0 + i * 64 + (t >> 3)) * 3072 + kSrcCol,
              Ks + i * 4096 + w * 512);
    #pragma unroll
    for (int i = 0; i < 2; ++i)
      gload16(vb + (size_t)(i * 32 + (t >> 4)) * 1024 + j0 + vSrcCol,
              VTs + i * 4096 + w * 512);
    __syncthreads();

    f32x4 s[8];
    #pragma unroll
    for (int n = 0; n < 8; ++n)
      s[n] = (f32x4){0.f, 0.f, 0.f, 0.f};
    #pragma unroll
    for (int ks = 0; ks < 2; ++ks) {
      #pragma unroll
      for (int n = 0; n < 8; ++n) {
        const bf16x8 bk = *(const bf16x8*)
            &Ks[(n * 16 + l15) * 64 + ((ks * 32 + l4 * 8) ^ ((l15 & 7) * 8))];
        s[n] = mfma16(aq[ks], bk, s[n]);
      }
    }

    float padv[8];
    #pragma unroll
    for (int n = 0; n < 8; ++n)
      padv[n] = (tb[j0 + n * 16 + l15] == 0) ? 1.f : 0.f;

    #pragma unroll
    for (int r = 0; r < 4; ++r) {
      const int rloc = l4 * 4 + r;
      const int qrow = q0 + w * 16 + rloc;
      float vals[8];
      float mx = -1e30f;
      #pragma unroll
      for (int n = 0; n < 8; ++n) {
        const int jg = j0 + n * 16 + l15;
        float v = s[n][r] * 0.125f;
        if (jg > qrow || padv[n] != 0.f) v = -1e9f;
        vals[n] = v;
        mx = fmaxf(mx, v);
      }
      #pragma unroll
      for (int d = 1; d < 16; d <<= 1) mx = fmaxf(mx, __shfl_xor(mx, d));
      const float newm = fmaxf(m_run[r], mx);
      const float sc = __expf(m_run[r] - newm);
      m_run[r] = newm;
      float rs = 0.f;
      #pragma unroll
      for (int n = 0; n < 8; ++n) {
        const float pv = __expf(vals[n] - newm);
        vals[n] = pv;
        rs += pv;
      }
      #pragma unroll
      for (int d = 1; d < 16; d <<= 1) rs += __shfl_xor(rs, d);
      l_run[r] = l_run[r] * sc + rs;
      #pragma unroll
      for (int nn = 0; nn < 4; ++nn) o[nn][r] = o[nn][r] * sc;
      #pragma unroll
      for (int n = 0; n < 8; ++n)
        Ps[(w * 16 + rloc) * 128 + ((n * 16 + l15) ^ (rloc * 8))] = f2b(vals[n]);
    }
    asm volatile("s_waitcnt lgkmcnt(0)" ::: "memory");

    #pragma unroll
    for (int ks = 0; ks < 4; ++ks) {
      const bf16x8 ap = *(const bf16x8*)
          &Ps[(w * 16 + l15) * 128 + ((ks * 32 + l4 * 8) ^ (l15 * 8))];
      #pragma unroll
      for (int nn = 0; nn < 4; ++nn) {
        const bf16x8 bv = *(const bf16x8*)
            &VTs[(nn * 16 + l15) * 128 + ((ks * 32 + l4 * 8) ^ (l15 * 8))];
        o[nn] = mfma16(ap, bv, o[nn]);
      }
    }
  }

  #pragma unroll
  for (int r = 0; r < 4; ++r) {
    const float inv = 1.0f / l_run[r];
    const int qrow = q0 + w * 16 + l4 * 4 + r;
    #pragma unroll
    for (int nn = 0; nn < 4; ++nn)
      ctx[(size_t)(b * 1024 + qrow) * 1024 + h * 64 + nn * 16 + l15] =
          f2b(o[nn][r] * inv);
  }

  // fused fixup: rows < P0 (leading pads) -> ctx = mean over all S of V.
  int loc = 1024;
  #pragma unroll 4
  for (int j = 0; j < 16; ++j) {
    const int idx = l * 16 + j;
    if (tb[idx] != 0) { loc = idx; break; }
  }
  #pragma unroll
  for (int d = 1; d < 64; d <<= 1) {
    const int o2 = __shfl_xor(loc, d);
    loc = (o2 < loc) ? o2 : loc;
  }
  const int P0 = loc;
  if (P0 > q0) {
    __syncthreads();
    const int rbeg = q0 + w * 16;
    if (P0 > rbeg) {
      const bf16* vrow = vb + (size_t)l * 1024;
      float sum = 0.f;
      for (int sIdx = 0; sIdx < 1024; sIdx += 4) {
        const ushort4 pv = *(const ushort4*)&vrow[sIdx];
        sum += u2f(pv.x) + u2f(pv.y) + u2f(pv.z) + u2f(pv.w);
      }
      const bf16 mv = f2b(sum * (1.0f / 1024.0f));
      const int rend = (P0 < rbeg + 16) ? P0 : (rbeg + 16);
      for (int q = rbeg; q < rend; ++q)
        ctx[(size_t)(b * 1024 + q) * 1024 + h * 64 + l] = mv;
    }
  }
}

// ---------------- host ----------------
extern "C" void kernel_launch(void* const* d_in, const int* in_sizes, int n_in,
                              void* d_out, int out_size, void* d_ws, size_t ws_size,
                              hipStream_t stream)
{
  (void)in_sizes; (void)n_in; (void)out_size;
  const int*   tokens = (const int*)d_in[0];
  const float* emb  = (const float*)d_in[1];
  const float* pe   = (const float*)d_in[2];
  const float* Wq   = (const float*)d_in[3];
  const float* Wk   = (const float*)d_in[4];
  const float* Wv   = (const float*)d_in[5];
  const float* Wo   = (const float*)d_in[6];
  const float* bo   = (const float*)d_in[7];
  const float* g1   = (const float*)d_in[8];
  const float* be1  = (const float*)d_in[9];
  const float* g2   = (const float*)d_in[10];
  const float* be2  = (const float*)d_in[11];
  const float* W1   = (const float*)d_in[12];
  const float* b1   = (const float*)d_in[13];
  const float* W2   = (const float*)d_in[14];
  const float* b2   = (const float*)d_in[15];
  const float* gf   = (const float*)d_in[16];
  const float* bff  = (const float*)d_in[17];
  const float* Wout = (const float*)d_in[18];
  const float* bout = (const float*)d_in[19];
  float* out = (float*)d_out;

  char* p = (char*)d_ws;
  auto alloc = [&](size_t bytes) {
    char* q = p;
    p += (bytes + 255) & ~(size_t)255;
    return q;
  };
  float* x    = (float*)alloc((size_t)2048 * 1024 * 4);
  bf16* Pp    = (bf16*)alloc((size_t)4 * 2048 * 1024 * 2);
  bf16* h     = (bf16*)alloc((size_t)2048 * 1024 * 2);
  bf16* qkv   = (bf16*)alloc((size_t)2048 * 3072 * 2);
  bf16* vT    = (bf16*)alloc((size_t)2048 * 1024 * 2);
  bf16* ctx   = (bf16*)alloc((size_t)2048 * 1024 * 2);
  bf16* ff    = (bf16*)alloc((size_t)2048 * 4096 * 2);
  bf16* WoutT = (bf16*)alloc((size_t)32000 * 1024 * 2);

  const size_t DD = (size_t)1024 * 1024;
  const size_t DF = (size_t)1024 * 4096;

  const size_t perLayerW = (3 * DD + DD + DF + DF) * 2;
  const size_t used = (size_t)(p - (char*)d_ws);
  const bool fullprep = ws_size >= used + 6 * perLayerW + 8192;
  const int NL = fullprep ? 6 : 1;
  bf16* WqkvT = (bf16*)alloc((size_t)NL * 3 * DD * 2);
  bf16* WoT   = (bf16*)alloc((size_t)NL * DD * 2);
  bf16* W1T   = (bf16*)alloc((size_t)NL * DF * 2);
  bf16* W2T   = (bf16*)alloc((size_t)NL * DF * 2);

  if (fullprep)
    prep_all_kernel<<<6 * 3072, 256, 0, stream>>>(
        Wq, Wk, Wv, Wo, W1, W2, WqkvT, WoT, W1T, W2T);

  // fused embed + ln1(layer 0)
  embed_ln_kernel<<<2048, 256, 0, stream>>>(tokens, emb, pe, g1, be1, x, h);

  for (int l = 0; l < 6; ++l) {
    const bf16* wqkvt; const bf16* wot; const bf16* w1t; const bf16* w2t;
    if (fullprep) {
      wqkvt = WqkvT + (size_t)l * 3 * DD;
      wot   = WoT   + (size_t)l * DD;
      w1t   = W1T   + (size_t)l * DF;
      w2t   = W2T   + (size_t)l * DF;
    } else {
      prep_layer_kernel<<<3072, 256, 0, stream>>>(
          Wq + l * DD, Wk + l * DD, Wv + l * DD, Wo + l * DD,
          W1 + l * DF, W2 + l * DF, WqkvT, WoT, W1T, W2T);
      wqkvt = WqkvT; wot = WoT; w1t = W1T; w2t = W2T;
    }

    // ln1 for layers >0: fold previous FFN2 partials (np=4)
    if (l > 0)
      ln_res_kernel<<<2048, 256, 0, stream>>>(
          x, Pp, 4, b2 + (l - 1) * 1024, g1 + l * 1024, be1 + l * 1024, h);

    // QKV: M=2048 N=3072 K=1024 -> 384 blocks; fused V-transpose epilogue
    gemm_pl<4, 0><<<dim3(16, 24, 1), 256, 0, stream>>>(
        h, 1024, wqkvt, 1024, qkv, 3072, (const float*)nullptr, vT, 1024);
    attn_kernel<<<dim3(8, 32), 512, 0, stream>>>(qkv, vT, tokens, ctx);
    // Wo: M=2048 N=1024 K=1024, splitK4 -> 512 blocks, bf16 partials
    gemm_pl<3, 0><<<dim3(16, 8, 4), 256, 0, stream>>>(
        ctx, 1024, wot, 1024, Pp, 1024, (const float*)nullptr,
        (bf16*)nullptr, 256);
    // ln2: x += sum(P0..3) + bo; h = LN(x)
    ln_res_kernel<<<2048, 256, 0, stream>>>(
        x, Pp, 4, bo + l * 1024, g2 + l * 1024, be2 + l * 1024, h);
    // FFN1: M=2048 N=4096 K=1024 -> 512 blocks
    gemm_pl<2, 0><<<dim3(16, 32, 1), 256, 0, stream>>>(
        h, 1024, w1t, 1024, ff, 4096, b1 + l * 4096, (bf16*)nullptr, 1024);
    // FFN2: M=2048 N=1024 K=4096, splitK4 -> 512 blocks, bf16 partials
    gemm_pl<3, 0><<<dim3(16, 8, 4), 256, 0, stream>>>(
        ff, 4096, w2t, 4096, Pp, 1024, (const float*)nullptr,
        (bf16*)nullptr, 1024);
  }

  // final LN folds layer-5 FFN2 partials
  ln_res_kernel<<<2048, 256, 0, stream>>>(x, Pp, 4, b2 + 5 * 1024, gf, bff, h);
  // Wout transpose IMMEDIATELY before logits -> WoutT is L3-hot for gemm256
  transpose_cast_kernel<<<dim3(500, 16), 256, 0, stream>>>(Wout, WoutT, 32000, 1024);
  // logits: M=2048 N=32000 K=1024 -> 256x128 single-barrier ring, 2000 blocks
  gemm256<<<dim3(8, 250), 512, 0, stream>>>(
      h, 1024, WoutT, 1024, out, 32000, bout, 1024);
}

// Round 16
// 1203.321 us; speedup vs baseline: 1.0333x; 1.0047x over previous
//
#include <hip/hip_runtime.h>
#include <hip/hip_bf16.h>
#include <stdint.h>

typedef __hip_bfloat16 bf16;
typedef __attribute__((ext_vector_type(8))) short bf16x8;
typedef __attribute__((ext_vector_type(4))) float f32x4;
typedef __attribute__((ext_vector_type(16))) float f32x16;

#define DEV static __device__ __forceinline__

DEV float b2f(bf16 v) { return __bfloat162float(v); }
DEV bf16  f2b(float v) { return __float2bfloat16(v); }

DEV float u2f(unsigned short u) {
  unsigned int x = (unsigned int)u << 16;
  float f;
  __builtin_memcpy(&f, &x, 4);
  return f;
}

DEV unsigned short f2u(float v) {
  bf16 b = f2b(v);
  unsigned short u;
  __builtin_memcpy(&u, &b, 2);
  return u;
}

DEV void gload16(const void* g, void* l) {
  __builtin_amdgcn_global_load_lds(
      (__attribute__((address_space(1))) void*)(void*)g,
      (__attribute__((address_space(3))) void*)l, 16, 0, 0);
}

DEV f32x4 mfma16(bf16x8 a, bf16x8 b, f32x4 c) {
  return __builtin_amdgcn_mfma_f32_16x16x32_bf16(a, b, c, 0, 0, 0);
}

// 32x32x16 bf16 MFMA: A/B lane layout row|col=lane&31, k=(lane>>5)*8+j;
// C/D: col=lane&31, row=(reg&3)+8*(reg>>2)+4*(lane>>5)  [guide m74/m101]
DEV f32x16 mfma32(bf16x8 a, bf16x8 b, f32x16 c) {
  return __builtin_amdgcn_mfma_f32_32x32x16_bf16(a, b, c, 0, 0, 0);
}

// -------- fused embed + layernorm (layer 0): x = emb[tok]*32+pe; h = LN(x) ----
__global__ __launch_bounds__(256) void embed_ln_kernel(
    const int* __restrict__ tok, const float* __restrict__ emb,
    const float* __restrict__ pe, const float* __restrict__ g,
    const float* __restrict__ be, float* __restrict__ x, bf16* __restrict__ h)
{
  const int r = blockIdx.x, t = threadIdx.x;
  const int s = r & 1023;
  const int tk = tok[r];
  const float4 e  = ((const float4*)(emb + (size_t)tk * 1024))[t];
  const float4 pp = ((const float4*)(pe + (size_t)s * 1024))[t];
  float4 v;
  v.x = e.x * 32.0f + pp.x;
  v.y = e.y * 32.0f + pp.y;
  v.z = e.z * 32.0f + pp.z;
  v.w = e.w * 32.0f + pp.w;

  float sm  = v.x + v.y + v.z + v.w;
  float sq = v.x * v.x + v.y * v.y + v.z * v.z + v.w * v.w;
  #pragma unroll
  for (int d = 1; d < 64; d <<= 1) {
    sm += __shfl_xor(sm, d);
    sq += __shfl_xor(sq, d);
  }
  __shared__ float red[8];
  const int w = t >> 6, l = t & 63;
  if (l == 0) { red[w] = sm; red[4 + w] = sq; }
  __syncthreads();
  sm = red[0] + red[1] + red[2] + red[3];
  sq = red[4] + red[5] + red[6] + red[7];
  const float mean = sm * (1.0f / 1024.0f);
  const float var  = sq * (1.0f / 1024.0f) - mean * mean;
  const float inv  = 1.0f / sqrtf(var + 1e-5f);

  ((float4*)(x + (size_t)r * 1024))[t] = v;
  bf16* hp = h + (size_t)r * 1024 + t * 4;
  const float* gp = g + t * 4;
  const float* bp = be + t * 4;
  const float vv[4] = {v.x, v.y, v.z, v.w};
  #pragma unroll
  for (int j = 0; j < 4; ++j)
    hp[j] = f2b((vv[j] - mean) * inv * gp[j] + bp[j]);
}

// -- fused residual + layernorm: x += sum(bf16 P[0..np)) + bias; h = LN(x)*g+be
__global__ __launch_bounds__(256) void ln_res_kernel(
    float* __restrict__ x, const bf16* __restrict__ P, int np,
    const float* __restrict__ bias, const float* __restrict__ g,
    const float* __restrict__ be, bf16* __restrict__ h)
{
  const int r = blockIdx.x, t = threadIdx.x;
  float4 v = ((const float4*)(x + (size_t)r * 1024))[t];
  for (int i = 0; i < np; ++i) {
    const ushort4 pv = ((const ushort4*)(P + ((size_t)i * 2048 + r) * 1024))[t];
    v.x += u2f(pv.x); v.y += u2f(pv.y); v.z += u2f(pv.z); v.w += u2f(pv.w);
  }
  const float4 bv = ((const float4*)bias)[t];
  v.x += bv.x; v.y += bv.y; v.z += bv.z; v.w += bv.w;

  float s  = v.x + v.y + v.z + v.w;
  float sq = v.x * v.x + v.y * v.y + v.z * v.z + v.w * v.w;
  #pragma unroll
  for (int d = 1; d < 64; d <<= 1) {
    s  += __shfl_xor(s, d);
    sq += __shfl_xor(sq, d);
  }
  __shared__ float red[8];
  const int w = t >> 6, l = t & 63;
  if (l == 0) { red[w] = s; red[4 + w] = sq; }
  __syncthreads();
  s  = red[0] + red[1] + red[2] + red[3];
  sq = red[4] + red[5] + red[6] + red[7];
  const float mean = s * (1.0f / 1024.0f);
  const float var  = sq * (1.0f / 1024.0f) - mean * mean;
  const float inv  = 1.0f / sqrtf(var + 1e-5f);

  ((float4*)(x + (size_t)r * 1024))[t] = v;
  bf16* hp = h + (size_t)r * 1024 + t * 4;
  const float* gp = g + t * 4;
  const float* bp = be + t * 4;
  const float vv[4] = {v.x, v.y, v.z, v.w};
  #pragma unroll
  for (int j = 0; j < 4; ++j)
    hp[j] = f2b((vv[j] - mean) * inv * gp[j] + bp[j]);
}

// ------------- 64x64 transpose+cast tile body -------------
DEV void transpose_tile(const float* __restrict__ in, bf16* __restrict__ out,
                        int ldin, int ldout, int r0, int c0, int t)
{
  __shared__ bf16 tile[64][64];
  #pragma unroll
  for (int i = 0; i < 4; ++i) {
    const int r = i * 16 + (t >> 4), c = (t & 15) * 4;
    const float4 v = *(const float4*)&in[(size_t)(r0 + r) * ldin + c0 + c];
    tile[r][c + 0] = f2b(v.x);
    tile[r][c + 1] = f2b(v.y);
    tile[r][c + 2] = f2b(v.z);
    tile[r][c + 3] = f2b(v.w);
  }
  __syncthreads();
  #pragma unroll
  for (int i = 0; i < 2; ++i) {
    const int oc = i * 32 + (t >> 3);
    const int rr = (t & 7) * 8;
    unsigned short tmp[8] __attribute__((aligned(16)));
    #pragma unroll
    for (int j = 0; j < 8; ++j)
      tmp[j] = ((const unsigned short*)tile)[(rr + j) * 64 + oc];
    *(uint4*)&out[(size_t)(c0 + oc) * ldout + r0 + rr] = *(const uint4*)tmp;
  }
}

// generic single-matrix transpose+cast (Wout, launched just before logits
// so WoutT is L3-hot when gemm256 consumes it — round-14 lesson)
__global__ __launch_bounds__(256) void transpose_cast_kernel(
    const float* __restrict__ in, bf16* __restrict__ out, int ldin, int ldout)
{
  transpose_tile(in, out, ldin, ldout, blockIdx.y * 64, blockIdx.x * 64, threadIdx.x);
}

// dispatch one 64x64 tile of the per-layer weight set (3072 tiles/layer)
DEV void prep_dispatch(int wid,
    const float* Wq, const float* Wk, const float* Wv, const float* Wo,
    const float* W1, const float* W2,
    bf16* WqkvT, bf16* WoT, bf16* W1T, bf16* W2T, int t)
{
  const float* src; bf16* dst; int ldin, ldout, tx, ty;
  if (wid < 768) {
    const int m = wid >> 8, tt = wid & 255;
    src = (m == 0) ? Wq : (m == 1) ? Wk : Wv;
    dst = WqkvT + (size_t)m * 1024 * 1024;
    ldin = 1024; ldout = 1024; tx = tt & 15; ty = tt >> 4;
  } else if (wid < 1024) {
    const int tt = wid - 768;
    src = Wo; dst = WoT; ldin = 1024; ldout = 1024; tx = tt & 15; ty = tt >> 4;
  } else if (wid < 2048) {
    const int tt = wid - 1024;
    src = W1; dst = W1T; ldin = 4096; ldout = 1024; tx = tt & 63; ty = tt >> 6;
  } else {
    const int tt = wid - 2048;
    src = W2; dst = W2T; ldin = 1024; ldout = 4096; tx = tt & 15; ty = tt >> 4;
  }
  transpose_tile(src, dst, ldin, ldout, ty * 64, tx * 64, t);
}

// per-layer weight prep (fallback path)
__global__ __launch_bounds__(256) void prep_layer_kernel(
    const float* __restrict__ Wq, const float* __restrict__ Wk,
    const float* __restrict__ Wv, const float* __restrict__ Wo,
    const float* __restrict__ W1, const float* __restrict__ W2,
    bf16* __restrict__ WqkvT, bf16* __restrict__ WoT,
    bf16* __restrict__ W1T, bf16* __restrict__ W2T)
{
  prep_dispatch(blockIdx.x, Wq, Wk, Wv, Wo, W1, W2,
                WqkvT, WoT, W1T, W2T, threadIdx.x);
}

// all-layers weight prep: 6*3072 blocks (Wout handled separately pre-logits)
__global__ __launch_bounds__(256) void prep_all_kernel(
    const float* __restrict__ Wq, const float* __restrict__ Wk,
    const float* __restrict__ Wv, const float* __restrict__ Wo,
    const float* __restrict__ W1, const float* __restrict__ W2,
    bf16* __restrict__ WqkvT, bf16* __restrict__ WoT,
    bf16* __restrict__ W1T, bf16* __restrict__ W2T)
{
  const size_t DD = (size_t)1024 * 1024, DF = (size_t)1024 * 4096;
  const int layer = blockIdx.x / 3072;
  const int wid = blockIdx.x - layer * 3072;
  prep_dispatch(wid,
      Wq + layer * DD, Wk + layer * DD, Wv + layer * DD, Wo + layer * DD,
      W1 + layer * DF, W2 + layer * DF,
      WqkvT + layer * 3 * DD, WoT + layer * DD,
      W1T + layer * DF, W2T + layer * DF, threadIdx.x);
}

// ------------- pipelined GEMM: C(MxN) = A(MxK,row) * BT(NxK,row)^T -------------
// BM=BN=128, BK=32; 3-buffer single-barrier ring (48 KB LDS -> 3 blocks/CU),
// counted vmcnt(4) (T4), verified conflict-free T2 XOR swizzle.
// MFMA 32x32x16 (2495 TF ceiling vs 2075 for 16x16): per-wave 2x2 fragments
// of 32x32, 8 MFMA + 8 ds_read_b128 per K-tile.
// EPI: 0 = bf16 store; 1 = +bias f32 store; 2 = gelu(acc+bias) bf16;
//      3 = bf16 K-slice partial store P[z][M][N]; 4 = QKV fused: cols<2048 ->
//          qkv bf16, cols>=2048 -> vT[(b*1024+hk)*1024+s] transposed write
// grid: (M/128, N/128, KSLICES), block 256 (4 waves), K-slice length ksl
template<int EPI, int SWZ>
__global__ __launch_bounds__(256, 3) void gemm_pl(
    const bf16* __restrict__ A, int lda,
    const bf16* __restrict__ BT, int ldb,
    void* __restrict__ Cp, int ldc,
    const float* __restrict__ bias,
    bf16* __restrict__ vTp,
    int ksl)
{
  __shared__ bf16 As[3][4096];
  __shared__ bf16 Bs[3][4096];
  const int t = threadIdx.x;

  int bm, bn;
  if constexpr (SWZ) {
    const int nbm = gridDim.x;
    const int nwg = nbm * gridDim.y;
    int wid = blockIdx.x + nbm * blockIdx.y;
    wid = (wid & 7) * (nwg >> 3) + (wid >> 3);
    bm = wid % nbm; bn = wid / nbm;
  } else {
    bm = blockIdx.x; bn = blockIdx.y;
  }

  const int w = t >> 6, l = t & 63;
  const int wr = (w >> 1) * 64, wc = (w & 1) * 64;
  const int l31 = l & 31, l5 = l >> 5;
  const int kbeg = blockIdx.z * ksl;
  const int NT = ksl >> 5;

  const int colblk = (((t & 3) ^ ((t >> 3) & 3))) * 8;
  const bf16* gA = A  + (size_t)(bm * 128 + (t >> 2)) * lda + colblk + kbeg;
  const bf16* gB = BT + (size_t)(bn * 128 + (t >> 2)) * ldb + colblk + kbeg;
  const int dst = w * 512;

  auto stage = [&](int tile, int buf) {
    const int k0 = tile * 32;
    gload16(gA + k0, &As[buf][dst]);
    gload16(gA + (size_t)64 * lda + k0, &As[buf][2048 + dst]);
    gload16(gB + k0, &Bs[buf][dst]);
    gload16(gB + (size_t)64 * ldb + k0, &Bs[buf][2048 + dst]);
  };

  f32x16 acc[2][2];
  #pragma unroll
  for (int m = 0; m < 2; ++m)
    #pragma unroll
    for (int n = 0; n < 2; ++n)
      acc[m][n] = (f32x16)(0.f);

  stage(0, 0);
  stage(1, 1);

  // read-side swizzle key: (row>>1)&3 with row = base32 + l31
  const int key = (l31 >> 1) & 3;
  const int rd0 = ((l5)     ^ key) * 8;   // ks=0 col-block
  const int rd1 = ((2 + l5) ^ key) * 8;   // ks=1 col-block

  int buf = 0;
  for (int kt = 0; kt < NT; ++kt) {
    if (kt + 1 < NT) asm volatile("s_waitcnt vmcnt(4)" ::: "memory");
    else             asm volatile("s_waitcnt vmcnt(0)" ::: "memory");
    __builtin_amdgcn_s_barrier();
    __builtin_amdgcn_sched_barrier(0);

    int nb = buf + 2; if (nb >= 3) nb -= 3;

    bf16x8 a0[2], a1[2], b0[2], b1[2];
    #pragma unroll
    for (int m = 0; m < 2; ++m) {
      const int row = (wr + m * 32 + l31) * 32;
      a0[m] = *(const bf16x8*)&As[buf][row + rd0];
      a1[m] = *(const bf16x8*)&As[buf][row + rd1];
    }
    #pragma unroll
    for (int n = 0; n < 2; ++n) {
      const int row = (wc + n * 32 + l31) * 32;
      b0[n] = *(const bf16x8*)&Bs[buf][row + rd0];
      b1[n] = *(const bf16x8*)&Bs[buf][row + rd1];
    }
    if (kt + 2 < NT) stage(kt + 2, nb);
    asm volatile("s_waitcnt lgkmcnt(0)" ::: "memory");
    __builtin_amdgcn_sched_barrier(0);

    __builtin_amdgcn_s_setprio(1);
    #pragma unroll
    for (int m = 0; m < 2; ++m)
      #pragma unroll
      for (int n = 0; n < 2; ++n) {
        acc[m][n] = mfma32(a0[m], b0[n], acc[m][n]);
        acc[m][n] = mfma32(a1[m], b1[n], acc[m][n]);
      }
    __builtin_amdgcn_s_setprio(0);
    __builtin_amdgcn_sched_barrier(0);

    if (++buf >= 3) buf = 0;
  }

  const int crow = bm * 128 + wr, ccol = bn * 128 + wc;
  #pragma unroll
  for (int n = 0; n < 2; ++n) {
    const int col = ccol + n * 32 + l31;
    float bv = 0.f;
    if (EPI == 1 || EPI == 2) bv = bias[col];
    #pragma unroll
    for (int m = 0; m < 2; ++m) {
      #pragma unroll
      for (int gq = 0; gq < 4; ++gq) {
        const int row = crow + m * 32 + gq * 8 + l5 * 4;
        if (EPI == 4 && ccol >= 2048) {
          const int b = row >> 10, s = row & 1023;
          const int hk = col - 2048;
          ushort4 pk;
          pk.x = f2u(acc[m][n][gq * 4 + 0]);
          pk.y = f2u(acc[m][n][gq * 4 + 1]);
          pk.z = f2u(acc[m][n][gq * 4 + 2]);
          pk.w = f2u(acc[m][n][gq * 4 + 3]);
          *(ushort4*)&vTp[((size_t)b * 1024 + hk) * 1024 + s] = pk;
          continue;
        }
        #pragma unroll
        for (int r = 0; r < 4; ++r) {
          const float v = acc[m][n][gq * 4 + r];
          if (EPI == 0 || EPI == 4) {
            ((bf16*)Cp)[(size_t)(row + r) * ldc + col] = f2b(v);
          } else if (EPI == 1) {
            ((float*)Cp)[(size_t)(row + r) * ldc + col] = v + bv;
          } else if (EPI == 2) {
            const float u = v + bv;
            const float gel = 0.5f * u * (1.0f + erff(u * 0.70710678118654752f));
            ((bf16*)Cp)[(size_t)(row + r) * ldc + col] = f2b(gel);
          } else {
            const int M = gridDim.x * 128;
            ((bf16*)Cp)[((size_t)blockIdx.z * M + row + r) * ldc + col] = f2b(v);
          }
        }
      }
    }
  }
}

// ------------- 256x128 8-wave single-barrier GEMM (logits) -------------
// MFMA 32x32x16, per-wave 64x64 = 2x2 fragments; two 4-read/4-MFMA phases per
// K-tile to cap VGPRs at 4 waves/SIMD. 3-buffer BK=32 ring (72 KB LDS),
// counted vmcnt(3), conflict-free XOR swizzle, XCD swizzle (nwg%8==0).
__global__ __launch_bounds__(512, 4) void gemm256(
    const bf16* __restrict__ A, int lda,
    const bf16* __restrict__ BT, int ldb,
    float* __restrict__ C, int ldc,
    const float* __restrict__ bias, int K)
{
  __shared__ bf16 As[3][8192];
  __shared__ bf16 Bs[3][4096];
  const int t = threadIdx.x;

  const int nbm = gridDim.x;
  const int nwg = nbm * gridDim.y;
  int wid = blockIdx.x + nbm * blockIdx.y;
  wid = (wid & 7) * (nwg >> 3) + (wid >> 3);
  const int bm = wid % nbm, bn = wid / nbm;

  const int w = t >> 6, l = t & 63;
  const int wm = w >> 1, wn = w & 1;
  const int l31 = l & 31, l5 = l >> 5;

  const int colblk = ((t & 3) ^ ((t >> 3) & 3)) * 8;
  const bf16* gA = A  + (size_t)(bm * 256 + (t >> 2)) * lda + colblk;
  const bf16* gB = BT + (size_t)(bn * 128 + (t >> 2)) * ldb + colblk;
  const int dst = w * 512;

  auto stage = [&](int kt, int buf) {
    const int k0 = kt * 32;
    gload16(gA + k0, &As[buf][dst]);
    gload16(gA + (size_t)128 * lda + k0, &As[buf][4096 + dst]);
    gload16(gB + k0, &Bs[buf][dst]);
  };

  const int key = (l31 >> 1) & 3;
  const int rd0 = ((l5)     ^ key) * 8;
  const int rd1 = ((2 + l5) ^ key) * 8;
  const int arow = wm * 64 + l31;   // + m*32
  const int brow = wn * 64 + l31;   // + n*32

  f32x16 acc[2][2];
  #pragma unroll
  for (int m = 0; m < 2; ++m)
    #pragma unroll
    for (int n = 0; n < 2; ++n)
      acc[m][n] = (f32x16)(0.f);

  const int NT = K >> 5;
  stage(0, 0);
  stage(1, 1);

  int buf = 0;
  for (int kt = 0; kt < NT; ++kt) {
    if (kt + 1 < NT) asm volatile("s_waitcnt vmcnt(3)" ::: "memory");
    else             asm volatile("s_waitcnt vmcnt(0)" ::: "memory");
    __builtin_amdgcn_s_barrier();
    __builtin_amdgcn_sched_barrier(0);

    int nb = buf + 2; if (nb >= 3) nb -= 3;

    // phase 0: ks=0 fragments + prefetch issue
    bf16x8 af[2], bfr[2];
    #pragma unroll
    for (int m = 0; m < 2; ++m)
      af[m] = *(const bf16x8*)&As[buf][(arow + m * 32) * 32 + rd0];
    #pragma unroll
    for (int n = 0; n < 2; ++n)
      bfr[n] = *(const bf16x8*)&Bs[buf][(brow + n * 32) * 32 + rd0];
    if (kt + 2 < NT) stage(kt + 2, nb);
    asm volatile("s_waitcnt lgkmcnt(0)" ::: "memory");
    __builtin_amdgcn_sched_barrier(0);
    __builtin_amdgcn_s_setprio(1);
    #pragma unroll
    for (int m = 0; m < 2; ++m)
      #pragma unroll
      for (int n = 0; n < 2; ++n)
        acc[m][n] = mfma32(af[m], bfr[n], acc[m][n]);
    __builtin_amdgcn_s_setprio(0);
    __builtin_amdgcn_sched_barrier(0);

    // phase 1: ks=1 fragments
    #pragma unroll
    for (int m = 0; m < 2; ++m)
      af[m] = *(const bf16x8*)&As[buf][(arow + m * 32) * 32 + rd1];
    #pragma unroll
    for (int n = 0; n < 2; ++n)
      bfr[n] = *(const bf16x8*)&Bs[buf][(brow + n * 32) * 32 + rd1];
    asm volatile("s_waitcnt lgkmcnt(0)" ::: "memory");
    __builtin_amdgcn_sched_barrier(0);
    __builtin_amdgcn_s_setprio(1);
    #pragma unroll
    for (int m = 0; m < 2; ++m)
      #pragma unroll
      for (int n = 0; n < 2; ++n)
        acc[m][n] = mfma32(af[m], bfr[n], acc[m][n]);
    __builtin_amdgcn_s_setprio(0);
    __builtin_amdgcn_sched_barrier(0);

    if (++buf >= 3) buf = 0;
  }

  #pragma unroll
  for (int n = 0; n < 2; ++n) {
    const int col = bn * 128 + wn * 64 + n * 32 + l31;
    const float bv = bias[col];
    #pragma unroll
    for (int m = 0; m < 2; ++m) {
      #pragma unroll
      for (int gq = 0; gq < 4; ++gq) {
        const int row = bm * 256 + wm * 64 + m * 32 + gq * 8 + l5 * 4;
        #pragma unroll
        for (int r = 0; r < 4; ++r)
          C[(size_t)(row + r) * ldc + col] = acc[m][n][gq * 4 + r] + bv;
      }
    }
  }
}

// ---------------- flash attention (8 waves x 16 q-rows, LDS XOR-swizzled) ----
__global__ __launch_bounds__(512) void attn_kernel(
    const bf16* __restrict__ qkv, const bf16* __restrict__ vT,
    const int* __restrict__ tokens, bf16* __restrict__ ctx)
{
  __shared__ bf16 Ks[128 * 64];
  __shared__ bf16 VTs[64 * 128];
  __shared__ bf16 Ps[128 * 128];

  const int qt = blockIdx.x;
  const int bh = blockIdx.y;
  const int b = bh >> 4, h = bh & 15;
  const int t = threadIdx.x, w = t >> 6, l = t & 63;
  const int l15 = l & 15, l4 = l >> 4;
  const int q0 = qt * 128;

  bf16x8 aq[2];
  #pragma unroll
  for (int ks = 0; ks < 2; ++ks)
    aq[ks] = *(const bf16x8*)(qkv +
        (size_t)(b * 1024 + q0 + w * 16 + l15) * 3072 +
        h * 64 + ks * 32 + l4 * 8);

  f32x4 o[4];
  float m_run[4], l_run[4];
  #pragma unroll
  for (int r = 0; r < 4; ++r) { m_run[r] = -1e30f; l_run[r] = 0.f; }
  #pragma unroll
  for (int nn = 0; nn < 4; ++nn)
    o[nn] = (f32x4){0.f, 0.f, 0.f, 0.f};

  const bf16* kb = qkv + (size_t)(b * 1024) * 3072 + 1024 + h * 64;
  const bf16* vb = vT + (size_t)(bh * 64) * 1024;
  const int* tb = tokens + b * 1024;

  const int kSrcCol = ((t & 7) ^ ((t >> 3) & 7)) * 8;
  const int vSrcCol = ((t & 15) ^ ((t >> 4) & 15)) * 8;

  for (int jt = 0; jt <= qt; ++jt) {
    const int j0 = jt * 128;
    __syncthreads();
    #pragma unroll
    for (int i = 0; i < 2; ++i)
      gload16(kb + (size_t)(j0 + i * 64 + (t >> 3)) * 3072 + kSrcCol,
              Ks + i * 4096 + w * 512);
    #pragma unroll
    for (int i = 0; i < 2; ++i)
      gload16(vb + (size_t)(i * 32 + (t >> 4)) * 1024 + j0 + vSrcCol,
              VTs + i * 4096 + w * 512);
    __syncthreads();

    f32x4 s[8];
    #pragma unroll
    for (int n = 0; n < 8; ++n)
      s[n] = (f32x4){0.f, 0.f, 0.f, 0.f};
    #pragma unroll
    for (int ks = 0; ks < 2; ++ks) {
      #pragma unroll
      for (int n = 0; n < 8; ++n) {
        const bf16x8 bk = *(const bf16x8*)
            &Ks[(n * 16 + l15) * 64 + ((ks * 32 + l4 * 8) ^ ((l15 & 7) * 8))];
        s[n] = mfma16(aq[ks], bk, s[n]);
      }
    }

    float padv[8];
    #pragma unroll
    for (int n = 0; n < 8; ++n)
      padv[n] = (tb[j0 + n * 16 + l15] == 0) ? 1.f : 0.f;

    #pragma unroll
    for (int r = 0; r < 4; ++r) {
      const int rloc = l4 * 4 + r;
      const int qrow = q0 + w * 16 + rloc;
      float vals[8];
      float mx = -1e30f;
      #pragma unroll
      for (int n = 0; n < 8; ++n) {
        const int jg = j0 + n * 16 + l15;
        float v = s[n][r] * 0.125f;
        if (jg > qrow || padv[n] != 0.f) v = -1e9f;
        vals[n] = v;
        mx = fmaxf(mx, v);
      }
      #pragma unroll
      for (int d = 1; d < 16; d <<= 1) mx = fmaxf(mx, __shfl_xor(mx, d));
      const float newm = fmaxf(m_run[r], mx);
      const float sc = __expf(m_run[r] - newm);
      m_run[r] = newm;
      float rs = 0.f;
      #pragma unroll
      for (int n = 0; n < 8; ++n) {
        const float pv = __expf(vals[n] - newm);
        vals[n] = pv;
        rs += pv;
      }
      #pragma unroll
      for (int d = 1; d < 16; d <<= 1) rs += __shfl_xor(rs, d);
      l_run[r] = l_run[r] * sc + rs;
      #pragma unroll
      for (int nn = 0; nn < 4; ++nn) o[nn][r] = o[nn][r] * sc;
      #pragma unroll
      for (int n = 0; n < 8; ++n)
        Ps[(w * 16 + rloc) * 128 + ((n * 16 + l15) ^ (rloc * 8))] = f2b(vals[n]);
    }
    asm volatile("s_waitcnt lgkmcnt(0)" ::: "memory");

    #pragma unroll
    for (int ks = 0; ks < 4; ++ks) {
      const bf16x8 ap = *(const bf16x8*)
          &Ps[(w * 16 + l15) * 128 + ((ks * 32 + l4 * 8) ^ (l15 * 8))];
      #pragma unroll
      for (int nn = 0; nn < 4; ++nn) {
        const bf16x8 bv = *(const bf16x8*)
            &VTs[(nn * 16 + l15) * 128 + ((ks * 32 + l4 * 8) ^ (l15 * 8))];
        o[nn] = mfma16(ap, bv, o[nn]);
      }
    }
  }

  #pragma unroll
  for (int r = 0; r < 4; ++r) {
    const float inv = 1.0f / l_run[r];
    const int qrow = q0 + w * 16 + l4 * 4 + r;
    #pragma unroll
    for (int nn = 0; nn < 4; ++nn)
      ctx[(size_t)(b * 1024 + qrow) * 1024 + h * 64 + nn * 16 + l15] =
          f2b(o[nn][r] * inv);
  }

  // fused fixup: rows < P0 (leading pads) -> ctx = mean over all S of V.
  int loc = 1024;
  #pragma unroll 4
  for (int j = 0; j < 16; ++j) {
    const int idx = l * 16 + j;
    if (tb[idx] != 0) { loc = idx; break; }
  }
  #pragma unroll
  for (int d = 1; d < 64; d <<= 1) {
    const int o2 = __shfl_xor(loc, d);
    loc = (o2 < loc) ? o2 : loc;
  }
  const int P0 = loc;
  if (P0 > q0) {
    __syncthreads();
    const int rbeg = q0 + w * 16;
    if (P0 > rbeg) {
      const bf16* vrow = vb + (size_t)l * 1024;
      float sum = 0.f;
      for (int sIdx = 0; sIdx < 1024; sIdx += 4) {
        const ushort4 pv = *(const ushort4*)&vrow[sIdx];
        sum += u2f(pv.x) + u2f(pv.y) + u2f(pv.z) + u2f(pv.w);
      }
      const bf16 mv = f2b(sum * (1.0f / 1024.0f));
      const int rend = (P0 < rbeg + 16) ? P0 : (rbeg + 16);
      for (int q = rbeg; q < rend; ++q)
        ctx[(size_t)(b * 1024 + q) * 1024 + h * 64 + l] = mv;
    }
  }
}

// ---------------- host ----------------
extern "C" void kernel_launch(void* const* d_in, const int* in_sizes, int n_in,
                              void* d_out, int out_size, void* d_ws, size_t ws_size,
                              hipStream_t stream)
{
  (void)in_sizes; (void)n_in; (void)out_size;
  const int*   tokens = (const int*)d_in[0];
  const float* emb  = (const float*)d_in[1];
  const float* pe   = (const float*)d_in[2];
  const float* Wq   = (const float*)d_in[3];
  const float* Wk   = (const float*)d_in[4];
  const float* Wv   = (const float*)d_in[5];
  const float* Wo   = (const float*)d_in[6];
  const float* bo   = (const float*)d_in[7];
  const float* g1   = (const float*)d_in[8];
  const float* be1  = (const float*)d_in[9];
  const float* g2   = (const float*)d_in[10];
  const float* be2  = (const float*)d_in[11];
  const float* W1   = (const float*)d_in[12];
  const float* b1   = (const float*)d_in[13];
  const float* W2   = (const float*)d_in[14];
  const float* b2   = (const float*)d_in[15];
  const float* gf   = (const float*)d_in[16];
  const float* bff  = (const float*)d_in[17];
  const float* Wout = (const float*)d_in[18];
  const float* bout = (const float*)d_in[19];
  float* out = (float*)d_out;

  char* p = (char*)d_ws;
  auto alloc = [&](size_t bytes) {
    char* q = p;
    p += (bytes + 255) & ~(size_t)255;
    return q;
  };
  float* x    = (float*)alloc((size_t)2048 * 1024 * 4);
  bf16* Pp    = (bf16*)alloc((size_t)4 * 2048 * 1024 * 2);
  bf16* h     = (bf16*)alloc((size_t)2048 * 1024 * 2);
  bf16* qkv   = (bf16*)alloc((size_t)2048 * 3072 * 2);
  bf16* vT    = (bf16*)alloc((size_t)2048 * 1024 * 2);
  bf16* ctx   = (bf16*)alloc((size_t)2048 * 1024 * 2);
  bf16* ff    = (bf16*)alloc((size_t)2048 * 4096 * 2);
  bf16* WoutT = (bf16*)alloc((size_t)32000 * 1024 * 2);

  const size_t DD = (size_t)1024 * 1024;
  const size_t DF = (size_t)1024 * 4096;

  const size_t perLayerW = (3 * DD + DD + DF + DF) * 2;
  const size_t used = (size_t)(p - (char*)d_ws);
  const bool fullprep = ws_size >= used + 6 * perLayerW + 8192;
  const int NL = fullprep ? 6 : 1;
  bf16* WqkvT = (bf16*)alloc((size_t)NL * 3 * DD * 2);
  bf16* WoT   = (bf16*)alloc((size_t)NL * DD * 2);
  bf16* W1T   = (bf16*)alloc((size_t)NL * DF * 2);
  bf16* W2T   = (bf16*)alloc((size_t)NL * DF * 2);

  if (fullprep)
    prep_all_kernel<<<6 * 3072, 256, 0, stream>>>(
        Wq, Wk, Wv, Wo, W1, W2, WqkvT, WoT, W1T, W2T);

  // fused embed + ln1(layer 0)
  embed_ln_kernel<<<2048, 256, 0, stream>>>(tokens, emb, pe, g1, be1, x, h);

  for (int l = 0; l < 6; ++l) {
    const bf16* wqkvt; const bf16* wot; const bf16* w1t; const bf16* w2t;
    if (fullprep) {
      wqkvt = WqkvT + (size_t)l * 3 * DD;
      wot   = WoT   + (size_t)l * DD;
      w1t   = W1T   + (size_t)l * DF;
      w2t   = W2T   + (size_t)l * DF;
    } else {
      prep_layer_kernel<<<3072, 256, 0, stream>>>(
          Wq + l * DD, Wk + l * DD, Wv + l * DD, Wo + l * DD,
          W1 + l * DF, W2 + l * DF, WqkvT, WoT, W1T, W2T);
      wqkvt = WqkvT; wot = WoT; w1t = W1T; w2t = W2T;
    }

    // ln1 for layers >0: fold previous FFN2 partials (np=4)
    if (l > 0)
      ln_res_kernel<<<2048, 256, 0, stream>>>(
          x, Pp, 4, b2 + (l - 1) * 1024, g1 + l * 1024, be1 + l * 1024, h);

    // QKV: M=2048 N=3072 K=1024 -> 384 blocks; fused V-transpose epilogue
    gemm_pl<4, 0><<<dim3(16, 24, 1), 256, 0, stream>>>(
        h, 1024, wqkvt, 1024, qkv, 3072, (const float*)nullptr, vT, 1024);
    attn_kernel<<<dim3(8, 32), 512, 0, stream>>>(qkv, vT, tokens, ctx);
    // Wo: M=2048 N=1024 K=1024, splitK4 -> 512 blocks, bf16 partials
    gemm_pl<3, 0><<<dim3(16, 8, 4), 256, 0, stream>>>(
        ctx, 1024, wot, 1024, Pp, 1024, (const float*)nullptr,
        (bf16*)nullptr, 256);
    // ln2: x += sum(P0..3) + bo; h = LN(x)
    ln_res_kernel<<<2048, 256, 0, stream>>>(
        x, Pp, 4, bo + l * 1024, g2 + l * 1024, be2 + l * 1024, h);
    // FFN1: M=2048 N=4096 K=1024 -> 512 blocks
    gemm_pl<2, 0><<<dim3(16, 32, 1), 256, 0, stream>>>(
        h, 1024, w1t, 1024, ff, 4096, b1 + l * 4096, (bf16*)nullptr, 1024);
    // FFN2: M=2048 N=1024 K=4096, splitK4 -> 512 blocks, bf16 partials
    gemm_pl<3, 0><<<dim3(16, 8, 4), 256, 0, stream>>>(
        ff, 4096, w2t, 4096, Pp, 1024, (const float*)nullptr,
        (bf16*)nullptr, 1024);
  }

  // final LN folds layer-5 FFN2 partials
  ln_res_kernel<<<2048, 256, 0, stream>>>(x, Pp, 4, b2 + 5 * 1024, gf, bff, h);
  // Wout transpose IMMEDIATELY before logits -> WoutT is L3-hot for gemm256
  transpose_cast_kernel<<<dim3(500, 16), 256, 0, stream>>>(Wout, WoutT, 32000, 1024);
  // logits: M=2048 N=32000 K=1024 -> 256x128 single-barrier ring, 2000 blocks
  gemm256<<<dim3(8, 250), 512, 0, stream>>>(
      h, 1024, WoutT, 1024, out, 32000, bout, 1024);
}

// Round 17
// 1201.891 us; speedup vs baseline: 1.0346x; 1.0012x over previous
//
#include <hip/hip_runtime.h>
#include <hip/hip_bf16.h>
#include <stdint.h>

typedef __hip_bfloat16 bf16;
typedef __attribute__((ext_vector_type(8))) short bf16x8;
typedef __attribute__((ext_vector_type(4))) float f32x4;
typedef __attribute__((ext_vector_type(16))) float f32x16;

#define DEV static __device__ __forceinline__

DEV float b2f(bf16 v) { return __bfloat162float(v); }
DEV bf16  f2b(float v) { return __float2bfloat16(v); }

DEV float u2f(unsigned short u) {
  unsigned int x = (unsigned int)u << 16;
  float f;
  __builtin_memcpy(&f, &x, 4);
  return f;
}

DEV unsigned short f2u(float v) {
  bf16 b = f2b(v);
  unsigned short u;
  __builtin_memcpy(&u, &b, 2);
  return u;
}

DEV void gload16(const void* g, void* l) {
  __builtin_amdgcn_global_load_lds(
      (__attribute__((address_space(1))) void*)(void*)g,
      (__attribute__((address_space(3))) void*)l, 16, 0, 0);
}

DEV f32x4 mfma16(bf16x8 a, bf16x8 b, f32x4 c) {
  return __builtin_amdgcn_mfma_f32_16x16x32_bf16(a, b, c, 0, 0, 0);
}

// 32x32x16 bf16 MFMA: A/B lane layout row|col=lane&31, k=(lane>>5)*8+j;
// C/D: col=lane&31, row=(reg&3)+8*(reg>>2)+4*(lane>>5)  [guide m74/m101]
DEV f32x16 mfma32(bf16x8 a, bf16x8 b, f32x16 c) {
  return __builtin_amdgcn_mfma_f32_32x32x16_bf16(a, b, c, 0, 0, 0);
}

// -------- fused embed + layernorm (layer 0): x = emb[tok]*32+pe; h = LN(x) ----
__global__ __launch_bounds__(256) void embed_ln_kernel(
    const int* __restrict__ tok, const float* __restrict__ emb,
    const float* __restrict__ pe, const float* __restrict__ g,
    const float* __restrict__ be, float* __restrict__ x, bf16* __restrict__ h)
{
  const int r = blockIdx.x, t = threadIdx.x;
  const int s = r & 1023;
  const int tk = tok[r];
  const float4 e  = ((const float4*)(emb + (size_t)tk * 1024))[t];
  const float4 pp = ((const float4*)(pe + (size_t)s * 1024))[t];
  float4 v;
  v.x = e.x * 32.0f + pp.x;
  v.y = e.y * 32.0f + pp.y;
  v.z = e.z * 32.0f + pp.z;
  v.w = e.w * 32.0f + pp.w;

  float sm  = v.x + v.y + v.z + v.w;
  float sq = v.x * v.x + v.y * v.y + v.z * v.z + v.w * v.w;
  #pragma unroll
  for (int d = 1; d < 64; d <<= 1) {
    sm += __shfl_xor(sm, d);
    sq += __shfl_xor(sq, d);
  }
  __shared__ float red[8];
  const int w = t >> 6, l = t & 63;
  if (l == 0) { red[w] = sm; red[4 + w] = sq; }
  __syncthreads();
  sm = red[0] + red[1] + red[2] + red[3];
  sq = red[4] + red[5] + red[6] + red[7];
  const float mean = sm * (1.0f / 1024.0f);
  const float var  = sq * (1.0f / 1024.0f) - mean * mean;
  const float inv  = 1.0f / sqrtf(var + 1e-5f);

  ((float4*)(x + (size_t)r * 1024))[t] = v;
  bf16* hp = h + (size_t)r * 1024 + t * 4;
  const float* gp = g + t * 4;
  const float* bp = be + t * 4;
  const float vv[4] = {v.x, v.y, v.z, v.w};
  #pragma unroll
  for (int j = 0; j < 4; ++j)
    hp[j] = f2b((vv[j] - mean) * inv * gp[j] + bp[j]);
}

// -- fused residual + layernorm: x += sum(bf16 P[0..np)) + bias; h = LN(x)*g+be
__global__ __launch_bounds__(256) void ln_res_kernel(
    float* __restrict__ x, const bf16* __restrict__ P, int np,
    const float* __restrict__ bias, const float* __restrict__ g,
    const float* __restrict__ be, bf16* __restrict__ h)
{
  const int r = blockIdx.x, t = threadIdx.x;
  float4 v = ((const float4*)(x + (size_t)r * 1024))[t];
  for (int i = 0; i < np; ++i) {
    const ushort4 pv = ((const ushort4*)(P + ((size_t)i * 2048 + r) * 1024))[t];
    v.x += u2f(pv.x); v.y += u2f(pv.y); v.z += u2f(pv.z); v.w += u2f(pv.w);
  }
  const float4 bv = ((const float4*)bias)[t];
  v.x += bv.x; v.y += bv.y; v.z += bv.z; v.w += bv.w;

  float s  = v.x + v.y + v.z + v.w;
  float sq = v.x * v.x + v.y * v.y + v.z * v.z + v.w * v.w;
  #pragma unroll
  for (int d = 1; d < 64; d <<= 1) {
    s  += __shfl_xor(s, d);
    sq += __shfl_xor(sq, d);
  }
  __shared__ float red[8];
  const int w = t >> 6, l = t & 63;
  if (l == 0) { red[w] = s; red[4 + w] = sq; }
  __syncthreads();
  s  = red[0] + red[1] + red[2] + red[3];
  sq = red[4] + red[5] + red[6] + red[7];
  const float mean = s * (1.0f / 1024.0f);
  const float var  = sq * (1.0f / 1024.0f) - mean * mean;
  const float inv  = 1.0f / sqrtf(var + 1e-5f);

  ((float4*)(x + (size_t)r * 1024))[t] = v;
  bf16* hp = h + (size_t)r * 1024 + t * 4;
  const float* gp = g + t * 4;
  const float* bp = be + t * 4;
  const float vv[4] = {v.x, v.y, v.z, v.w};
  #pragma unroll
  for (int j = 0; j < 4; ++j)
    hp[j] = f2b((vv[j] - mean) * inv * gp[j] + bp[j]);
}

// ------------- 64x64 transpose+cast tile body -------------
DEV void transpose_tile(const float* __restrict__ in, bf16* __restrict__ out,
                        int ldin, int ldout, int r0, int c0, int t)
{
  __shared__ bf16 tile[64][64];
  #pragma unroll
  for (int i = 0; i < 4; ++i) {
    const int r = i * 16 + (t >> 4), c = (t & 15) * 4;
    const float4 v = *(const float4*)&in[(size_t)(r0 + r) * ldin + c0 + c];
    tile[r][c + 0] = f2b(v.x);
    tile[r][c + 1] = f2b(v.y);
    tile[r][c + 2] = f2b(v.z);
    tile[r][c + 3] = f2b(v.w);
  }
  __syncthreads();
  #pragma unroll
  for (int i = 0; i < 2; ++i) {
    const int oc = i * 32 + (t >> 3);
    const int rr = (t & 7) * 8;
    unsigned short tmp[8] __attribute__((aligned(16)));
    #pragma unroll
    for (int j = 0; j < 8; ++j)
      tmp[j] = ((const unsigned short*)tile)[(rr + j) * 64 + oc];
    *(uint4*)&out[(size_t)(c0 + oc) * ldout + r0 + rr] = *(const uint4*)tmp;
  }
}

// generic single-matrix transpose+cast (Wout, launched just before logits
// so WoutT is L3-hot when gemm256 consumes it — round-14 lesson)
__global__ __launch_bounds__(256) void transpose_cast_kernel(
    const float* __restrict__ in, bf16* __restrict__ out, int ldin, int ldout)
{
  transpose_tile(in, out, ldin, ldout, blockIdx.y * 64, blockIdx.x * 64, threadIdx.x);
}

// dispatch one 64x64 tile of the per-layer weight set (3072 tiles/layer)
DEV void prep_dispatch(int wid,
    const float* Wq, const float* Wk, const float* Wv, const float* Wo,
    const float* W1, const float* W2,
    bf16* WqkvT, bf16* WoT, bf16* W1T, bf16* W2T, int t)
{
  const float* src; bf16* dst; int ldin, ldout, tx, ty;
  if (wid < 768) {
    const int m = wid >> 8, tt = wid & 255;
    src = (m == 0) ? Wq : (m == 1) ? Wk : Wv;
    dst = WqkvT + (size_t)m * 1024 * 1024;
    ldin = 1024; ldout = 1024; tx = tt & 15; ty = tt >> 4;
  } else if (wid < 1024) {
    const int tt = wid - 768;
    src = Wo; dst = WoT; ldin = 1024; ldout = 1024; tx = tt & 15; ty = tt >> 4;
  } else if (wid < 2048) {
    const int tt = wid - 1024;
    src = W1; dst = W1T; ldin = 4096; ldout = 1024; tx = tt & 63; ty = tt >> 6;
  } else {
    const int tt = wid - 2048;
    src = W2; dst = W2T; ldin = 1024; ldout = 4096; tx = tt & 15; ty = tt >> 4;
  }
  transpose_tile(src, dst, ldin, ldout, ty * 64, tx * 64, t);
}

// per-layer weight prep (fallback path)
__global__ __launch_bounds__(256) void prep_layer_kernel(
    const float* __restrict__ Wq, const float* __restrict__ Wk,
    const float* __restrict__ Wv, const float* __restrict__ Wo,
    const float* __restrict__ W1, const float* __restrict__ W2,
    bf16* __restrict__ WqkvT, bf16* __restrict__ WoT,
    bf16* __restrict__ W1T, bf16* __restrict__ W2T)
{
  prep_dispatch(blockIdx.x, Wq, Wk, Wv, Wo, W1, W2,
                WqkvT, WoT, W1T, W2T, threadIdx.x);
}

// all-layers weight prep: 6*3072 blocks (Wout handled separately pre-logits)
__global__ __launch_bounds__(256) void prep_all_kernel(
    const float* __restrict__ Wq, const float* __restrict__ Wk,
    const float* __restrict__ Wv, const float* __restrict__ Wo,
    const float* __restrict__ W1, const float* __restrict__ W2,
    bf16* __restrict__ WqkvT, bf16* __restrict__ WoT,
    bf16* __restrict__ W1T, bf16* __restrict__ W2T)
{
  const size_t DD = (size_t)1024 * 1024, DF = (size_t)1024 * 4096;
  const int layer = blockIdx.x / 3072;
  const int wid = blockIdx.x - layer * 3072;
  prep_dispatch(wid,
      Wq + layer * DD, Wk + layer * DD, Wv + layer * DD, Wo + layer * DD,
      W1 + layer * DF, W2 + layer * DF,
      WqkvT + layer * 3 * DD, WoT + layer * DD,
      W1T + layer * DF, W2T + layer * DF, threadIdx.x);
}

// ------------- pipelined GEMM: C(MxN) = A(MxK,row) * BT(NxK,row)^T -------------
// BM=BN=128, BK=32; 3-buffer single-barrier ring (48 KB LDS -> 3 blocks/CU),
// counted vmcnt(4) (T4). MFMA 32x32x16 (round-16 win: -14 us vs 16x16).
// EPI: 0 = bf16 store; 1 = +bias f32 store; 2 = gelu(acc+bias) bf16;
//      3 = bf16 K-slice partial store P[z][M][N]; 4 = QKV fused: cols<2048 ->
//          qkv bf16, cols>=2048 -> vT[(b*1024+hk)*1024+s] transposed write
// grid: (M/128, N/128, KSLICES), block 256 (4 waves), K-slice length ksl
template<int EPI, int SWZ>
__global__ __launch_bounds__(256, 3) void gemm_pl(
    const bf16* __restrict__ A, int lda,
    const bf16* __restrict__ BT, int ldb,
    void* __restrict__ Cp, int ldc,
    const float* __restrict__ bias,
    bf16* __restrict__ vTp,
    int ksl)
{
  __shared__ bf16 As[3][4096];
  __shared__ bf16 Bs[3][4096];
  const int t = threadIdx.x;

  int bm, bn;
  if constexpr (SWZ) {
    const int nbm = gridDim.x;
    const int nwg = nbm * gridDim.y;
    int wid = blockIdx.x + nbm * blockIdx.y;
    wid = (wid & 7) * (nwg >> 3) + (wid >> 3);
    bm = wid % nbm; bn = wid / nbm;
  } else {
    bm = blockIdx.x; bn = blockIdx.y;
  }

  const int w = t >> 6, l = t & 63;
  const int wr = (w >> 1) * 64, wc = (w & 1) * 64;
  const int l31 = l & 31, l5 = l >> 5;
  const int kbeg = blockIdx.z * ksl;
  const int NT = ksl >> 5;

  const int colblk = (((t & 3) ^ ((t >> 3) & 3))) * 8;
  const bf16* gA = A  + (size_t)(bm * 128 + (t >> 2)) * lda + colblk + kbeg;
  const bf16* gB = BT + (size_t)(bn * 128 + (t >> 2)) * ldb + colblk + kbeg;
  const int dst = w * 512;

  auto stage = [&](int tile, int buf) {
    const int k0 = tile * 32;
    gload16(gA + k0, &As[buf][dst]);
    gload16(gA + (size_t)64 * lda + k0, &As[buf][2048 + dst]);
    gload16(gB + k0, &Bs[buf][dst]);
    gload16(gB + (size_t)64 * ldb + k0, &Bs[buf][2048 + dst]);
  };

  f32x16 acc[2][2];
  #pragma unroll
  for (int m = 0; m < 2; ++m)
    #pragma unroll
    for (int n = 0; n < 2; ++n)
      acc[m][n] = (f32x16)(0.f);

  stage(0, 0);
  stage(1, 1);

  const int key = (l31 >> 1) & 3;
  const int rd0 = ((l5)     ^ key) * 8;   // ks=0 col-block
  const int rd1 = ((2 + l5) ^ key) * 8;   // ks=1 col-block

  int buf = 0;
  for (int kt = 0; kt < NT; ++kt) {
    if (kt + 1 < NT) asm volatile("s_waitcnt vmcnt(4)" ::: "memory");
    else             asm volatile("s_waitcnt vmcnt(0)" ::: "memory");
    __builtin_amdgcn_s_barrier();
    __builtin_amdgcn_sched_barrier(0);

    int nb = buf + 2; if (nb >= 3) nb -= 3;

    bf16x8 a0[2], a1[2], b0[2], b1[2];
    #pragma unroll
    for (int m = 0; m < 2; ++m) {
      const int row = (wr + m * 32 + l31) * 32;
      a0[m] = *(const bf16x8*)&As[buf][row + rd0];
      a1[m] = *(const bf16x8*)&As[buf][row + rd1];
    }
    #pragma unroll
    for (int n = 0; n < 2; ++n) {
      const int row = (wc + n * 32 + l31) * 32;
      b0[n] = *(const bf16x8*)&Bs[buf][row + rd0];
      b1[n] = *(const bf16x8*)&Bs[buf][row + rd1];
    }
    if (kt + 2 < NT) stage(kt + 2, nb);
    asm volatile("s_waitcnt lgkmcnt(0)" ::: "memory");
    __builtin_amdgcn_sched_barrier(0);

    __builtin_amdgcn_s_setprio(1);
    #pragma unroll
    for (int m = 0; m < 2; ++m)
      #pragma unroll
      for (int n = 0; n < 2; ++n) {
        acc[m][n] = mfma32(a0[m], b0[n], acc[m][n]);
        acc[m][n] = mfma32(a1[m], b1[n], acc[m][n]);
      }
    __builtin_amdgcn_s_setprio(0);
    __builtin_amdgcn_sched_barrier(0);

    if (++buf >= 3) buf = 0;
  }

  const int crow = bm * 128 + wr, ccol = bn * 128 + wc;
  #pragma unroll
  for (int n = 0; n < 2; ++n) {
    const int col = ccol + n * 32 + l31;
    float bv = 0.f;
    if (EPI == 1 || EPI == 2) bv = bias[col];
    #pragma unroll
    for (int m = 0; m < 2; ++m) {
      #pragma unroll
      for (int gq = 0; gq < 4; ++gq) {
        const int row = crow + m * 32 + gq * 8 + l5 * 4;
        if (EPI == 4 && ccol >= 2048) {
          const int b = row >> 10, s = row & 1023;
          const int hk = col - 2048;
          ushort4 pk;
          pk.x = f2u(acc[m][n][gq * 4 + 0]);
          pk.y = f2u(acc[m][n][gq * 4 + 1]);
          pk.z = f2u(acc[m][n][gq * 4 + 2]);
          pk.w = f2u(acc[m][n][gq * 4 + 3]);
          *(ushort4*)&vTp[((size_t)b * 1024 + hk) * 1024 + s] = pk;
          continue;
        }
        #pragma unroll
        for (int r = 0; r < 4; ++r) {
          const float v = acc[m][n][gq * 4 + r];
          if (EPI == 0 || EPI == 4) {
            ((bf16*)Cp)[(size_t)(row + r) * ldc + col] = f2b(v);
          } else if (EPI == 1) {
            ((float*)Cp)[(size_t)(row + r) * ldc + col] = v + bv;
          } else if (EPI == 2) {
            const float u = v + bv;
            const float gel = 0.5f * u * (1.0f + erff(u * 0.70710678118654752f));
            ((bf16*)Cp)[(size_t)(row + r) * ldc + col] = f2b(gel);
          } else {
            const int M = gridDim.x * 128;
            ((bf16*)Cp)[((size_t)blockIdx.z * M + row + r) * ldc + col] = f2b(v);
          }
        }
      }
    }
  }
}

// ------------- 256x128 8-wave single-barrier GEMM (logits; round-15 best) ----
// MFMA 16x16x32 (2-way LDS aliasing = free; 32x32 geometry is inherent 4-way
// here — measured round 16). 8 waves 4m x 2n, per-wave 64x64; 3-buffer BK=32
// ring (72 KB LDS), counted vmcnt(3), XCD swizzle (nwg%8==0). 512 threads.
__global__ __launch_bounds__(512, 4) void gemm256(
    const bf16* __restrict__ A, int lda,
    const bf16* __restrict__ BT, int ldb,
    float* __restrict__ C, int ldc,
    const float* __restrict__ bias, int K)
{
  __shared__ bf16 As[3][8192];
  __shared__ bf16 Bs[3][4096];
  const int t = threadIdx.x;

  const int nbm = gridDim.x;
  const int nwg = nbm * gridDim.y;
  int wid = blockIdx.x + nbm * blockIdx.y;
  wid = (wid & 7) * (nwg >> 3) + (wid >> 3);
  const int bm = wid % nbm, bn = wid / nbm;

  const int w = t >> 6, l = t & 63;
  const int wm = w >> 1, wn = w & 1;
  const int l15 = l & 15, l4 = l >> 4;

  const int colblk = ((t & 3) ^ ((t >> 3) & 3)) * 8;
  const bf16* gA = A  + (size_t)(bm * 256 + (t >> 2)) * lda + colblk;
  const bf16* gB = BT + (size_t)(bn * 128 + (t >> 2)) * ldb + colblk;
  const int dst = w * 512;

  auto stage = [&](int kt, int buf) {
    const int k0 = kt * 32;
    gload16(gA + k0, &As[buf][dst]);
    gload16(gA + (size_t)128 * lda + k0, &As[buf][4096 + dst]);
    gload16(gB + k0, &Bs[buf][dst]);
  };

  const int rd = (l4 ^ ((l15 >> 1) & 3)) * 8;
  const int arow = wm * 64 + l15;
  const int brow = wn * 64 + l15;

  f32x4 acc[4][4];
  #pragma unroll
  for (int m = 0; m < 4; ++m)
    #pragma unroll
    for (int n = 0; n < 4; ++n)
      acc[m][n] = (f32x4){0.f, 0.f, 0.f, 0.f};

  const int NT = K >> 5;
  stage(0, 0);
  stage(1, 1);

  int buf = 0;
  for (int kt = 0; kt < NT; ++kt) {
    if (kt + 1 < NT) asm volatile("s_waitcnt vmcnt(3)" ::: "memory");
    else             asm volatile("s_waitcnt vmcnt(0)" ::: "memory");
    __builtin_amdgcn_s_barrier();
    __builtin_amdgcn_sched_barrier(0);

    int nb = buf + 2; if (nb >= 3) nb -= 3;

    bf16x8 af[4], bfr[4];
    #pragma unroll
    for (int n = 0; n < 4; ++n)
      bfr[n] = *(const bf16x8*)&Bs[buf][(brow + n * 16) * 32 + rd];
    #pragma unroll
    for (int m = 0; m < 4; ++m)
      af[m] = *(const bf16x8*)&As[buf][(arow + m * 16) * 32 + rd];
    if (kt + 2 < NT) stage(kt + 2, nb);
    asm volatile("s_waitcnt lgkmcnt(0)" ::: "memory");
    __builtin_amdgcn_sched_barrier(0);

    __builtin_amdgcn_s_setprio(1);
    #pragma unroll
    for (int m = 0; m < 4; ++m)
      #pragma unroll
      for (int n = 0; n < 4; ++n)
        acc[m][n] = mfma16(af[m], bfr[n], acc[m][n]);
    __builtin_amdgcn_s_setprio(0);
    __builtin_amdgcn_sched_barrier(0);

    if (++buf >= 3) buf = 0;
  }

  #pragma unroll
  for (int n = 0; n < 4; ++n) {
    const int col = bn * 128 + wn * 64 + n * 16 + l15;
    const float bv = bias[col];
    #pragma unroll
    for (int m = 0; m < 4; ++m) {
      const int row = bm * 256 + wm * 64 + m * 16 + l4 * 4;
      #pragma unroll
      for (int r = 0; r < 4; ++r)
        C[(size_t)(row + r) * ldc + col] = acc[m][n][r] + bv;
    }
  }
}

// ---------------- flash attention (8 waves x 16 q-rows, LDS XOR-swizzled) ----
__global__ __launch_bounds__(512) void attn_kernel(
    const bf16* __restrict__ qkv, const bf16* __restrict__ vT,
    const int* __restrict__ tokens, bf16* __restrict__ ctx)
{
  __shared__ bf16 Ks[128 * 64];
  __shared__ bf16 VTs[64 * 128];
  __shared__ bf16 Ps[128 * 128];

  const int qt = blockIdx.x;
  const int bh = blockIdx.y;
  const int b = bh >> 4, h = bh & 15;
  const int t = threadIdx.x, w = t >> 6, l = t & 63;
  const int l15 = l & 15, l4 = l >> 4;
  const int q0 = qt * 128;

  bf16x8 aq[2];
  #pragma unroll
  for (int ks = 0; ks < 2; ++ks)
    aq[ks] = *(const bf16x8*)(qkv +
        (size_t)(b * 1024 + q0 + w * 16 + l15) * 3072 +
        h * 64 + ks * 32 + l4 * 8);

  f32x4 o[4];
  float m_run[4], l_run[4];
  #pragma unroll
  for (int r = 0; r < 4; ++r) { m_run[r] = -1e30f; l_run[r] = 0.f; }
  #pragma unroll
  for (int nn = 0; nn < 4; ++nn)
    o[nn] = (f32x4){0.f, 0.f, 0.f, 0.f};

  const bf16* kb = qkv + (size_t)(b * 1024) * 3072 + 1024 + h * 64;
  const bf16* vb = vT + (size_t)(bh * 64) * 1024;
  const int* tb = tokens + b * 1024;

  const int kSrcCol = ((t & 7) ^ ((t >> 3) & 7)) * 8;
  const int vSrcCol = ((t & 15) ^ ((t >> 4) & 15)) * 8;

  for (int jt = 0; jt <= qt; ++jt) {
    const int j0 = jt * 128;
    __syncthreads();
    #pragma unroll
    for (int i = 0; i < 2; ++i)
      gload16(kb + (size_t)(j0 + i * 64 + (t >> 3)) * 3072 + kSrcCol,
              Ks + i * 4096 + w * 512);
    #pragma unroll
    for (int i = 0; i < 2; ++i)
      gload16(vb + (size_t)(i * 32 + (t >> 4)) * 1024 + j0 + vSrcCol,
              VTs + i * 4096 + w * 512);
    __syncthreads();

    f32x4 s[8];
    #pragma unroll
    for (int n = 0; n < 8; ++n)
      s[n] = (f32x4){0.f, 0.f, 0.f, 0.f};
    #pragma unroll
    for (int ks = 0; ks < 2; ++ks) {
      #pragma unroll
      for (int n = 0; n < 8; ++n) {
        const bf16x8 bk = *(const bf16x8*)
            &Ks[(n * 16 + l15) * 64 + ((ks * 32 + l4 * 8) ^ ((l15 & 7) * 8))];
        s[n] = mfma16(aq[ks], bk, s[n]);
      }
    }

    float padv[8];
    #pragma unroll
    for (int n = 0; n < 8; ++n)
      padv[n] = (tb[j0 + n * 16 + l15] == 0) ? 1.f : 0.f;

    #pragma unroll
    for (int r = 0; r < 4; ++r) {
      const int rloc = l4 * 4 + r;
      const int qrow = q0 + w * 16 + rloc;
      float vals[8];
      float mx = -1e30f;
      #pragma unroll
      for (int n = 0; n < 8; ++n) {
        const int jg = j0 + n * 16 + l15;
        float v = s[n][r] * 0.125f;
        if (jg > qrow || padv[n] != 0.f) v = -1e9f;
        vals[n] = v;
        mx = fmaxf(mx, v);
      }
      #pragma unroll
      for (int d = 1; d < 16; d <<= 1) mx = fmaxf(mx, __shfl_xor(mx, d));
      const float newm = fmaxf(m_run[r], mx);
      const float sc = __expf(m_run[r] - newm);
      m_run[r] = newm;
      float rs = 0.f;
      #pragma unroll
      for (int n = 0; n < 8; ++n) {
        const float pv = __expf(vals[n] - newm);
        vals[n] = pv;
        rs += pv;
      }
      #pragma unroll
      for (int d = 1; d < 16; d <<= 1) rs += __shfl_xor(rs, d);
      l_run[r] = l_run[r] * sc + rs;
      #pragma unroll
      for (int nn = 0; nn < 4; ++nn) o[nn][r] = o[nn][r] * sc;
      #pragma unroll
      for (int n = 0; n < 8; ++n)
        Ps[(w * 16 + rloc) * 128 + ((n * 16 + l15) ^ (rloc * 8))] = f2b(vals[n]);
    }
    asm volatile("s_waitcnt lgkmcnt(0)" ::: "memory");

    #pragma unroll
    for (int ks = 0; ks < 4; ++ks) {
      const bf16x8 ap = *(const bf16x8*)
          &Ps[(w * 16 + l15) * 128 + ((ks * 32 + l4 * 8) ^ (l15 * 8))];
      #pragma unroll
      for (int nn = 0; nn < 4; ++nn) {
        const bf16x8 bv = *(const bf16x8*)
            &VTs[(nn * 16 + l15) * 128 + ((ks * 32 + l4 * 8) ^ (l15 * 8))];
        o[nn] = mfma16(ap, bv, o[nn]);
      }
    }
  }

  #pragma unroll
  for (int r = 0; r < 4; ++r) {
    const float inv = 1.0f / l_run[r];
    const int qrow = q0 + w * 16 + l4 * 4 + r;
    #pragma unroll
    for (int nn = 0; nn < 4; ++nn)
      ctx[(size_t)(b * 1024 + qrow) * 1024 + h * 64 + nn * 16 + l15] =
          f2b(o[nn][r] * inv);
  }

  // fused fixup: rows < P0 (leading pads) -> ctx = mean over all S of V.
  int loc = 1024;
  #pragma unroll 4
  for (int j = 0; j < 16; ++j) {
    const int idx = l * 16 + j;
    if (tb[idx] != 0) { loc = idx; break; }
  }
  #pragma unroll
  for (int d = 1; d < 64; d <<= 1) {
    const int o2 = __shfl_xor(loc, d);
    loc = (o2 < loc) ? o2 : loc;
  }
  const int P0 = loc;
  if (P0 > q0) {
    __syncthreads();
    const int rbeg = q0 + w * 16;
    if (P0 > rbeg) {
      const bf16* vrow = vb + (size_t)l * 1024;
      float sum = 0.f;
      for (int sIdx = 0; sIdx < 1024; sIdx += 4) {
        const ushort4 pv = *(const ushort4*)&vrow[sIdx];
        sum += u2f(pv.x) + u2f(pv.y) + u2f(pv.z) + u2f(pv.w);
      }
      const bf16 mv = f2b(sum * (1.0f / 1024.0f));
      const int rend = (P0 < rbeg + 16) ? P0 : (rbeg + 16);
      for (int q = rbeg; q < rend; ++q)
        ctx[(size_t)(b * 1024 + q) * 1024 + h * 64 + l] = mv;
    }
  }
}

// ---------------- host ----------------
extern "C" void kernel_launch(void* const* d_in, const int* in_sizes, int n_in,
                              void* d_out, int out_size, void* d_ws, size_t ws_size,
                              hipStream_t stream)
{
  (void)in_sizes; (void)n_in; (void)out_size;
  const int*   tokens = (const int*)d_in[0];
  const float* emb  = (const float*)d_in[1];
  const float* pe   = (const float*)d_in[2];
  const float* Wq   = (const float*)d_in[3];
  const float* Wk   = (const float*)d_in[4];
  const float* Wv   = (const float*)d_in[5];
  const float* Wo   = (const float*)d_in[6];
  const float* bo   = (const float*)d_in[7];
  const float* g1   = (const float*)d_in[8];
  const float* be1  = (const float*)d_in[9];
  const float* g2   = (const float*)d_in[10];
  const float* be2  = (const float*)d_in[11];
  const float* W1   = (const float*)d_in[12];
  const float* b1   = (const float*)d_in[13];
  const float* W2   = (const float*)d_in[14];
  const float* b2   = (const float*)d_in[15];
  const float* gf   = (const float*)d_in[16];
  const float* bff  = (const float*)d_in[17];
  const float* Wout = (const float*)d_in[18];
  const float* bout = (const float*)d_in[19];
  float* out = (float*)d_out;

  char* p = (char*)d_ws;
  auto alloc = [&](size_t bytes) {
    char* q = p;
    p += (bytes + 255) & ~(size_t)255;
    return q;
  };
  float* x    = (float*)alloc((size_t)2048 * 1024 * 4);
  bf16* Pp    = (bf16*)alloc((size_t)4 * 2048 * 1024 * 2);
  bf16* h     = (bf16*)alloc((size_t)2048 * 1024 * 2);
  bf16* qkv   = (bf16*)alloc((size_t)2048 * 3072 * 2);
  bf16* vT    = (bf16*)alloc((size_t)2048 * 1024 * 2);
  bf16* ctx   = (bf16*)alloc((size_t)2048 * 1024 * 2);
  bf16* ff    = (bf16*)alloc((size_t)2048 * 4096 * 2);
  bf16* WoutT = (bf16*)alloc((size_t)32000 * 1024 * 2);

  const size_t DD = (size_t)1024 * 1024;
  const size_t DF = (size_t)1024 * 4096;

  const size_t perLayerW = (3 * DD + DD + DF + DF) * 2;
  const size_t used = (size_t)(p - (char*)d_ws);
  const bool fullprep = ws_size >= used + 6 * perLayerW + 8192;
  const int NL = fullprep ? 6 : 1;
  bf16* WqkvT = (bf16*)alloc((size_t)NL * 3 * DD * 2);
  bf16* WoT   = (bf16*)alloc((size_t)NL * DD * 2);
  bf16* W1T   = (bf16*)alloc((size_t)NL * DF * 2);
  bf16* W2T   = (bf16*)alloc((size_t)NL * DF * 2);

  if (fullprep)
    prep_all_kernel<<<6 * 3072, 256, 0, stream>>>(
        Wq, Wk, Wv, Wo, W1, W2, WqkvT, WoT, W1T, W2T);

  // fused embed + ln1(layer 0)
  embed_ln_kernel<<<2048, 256, 0, stream>>>(tokens, emb, pe, g1, be1, x, h);

  for (int l = 0; l < 6; ++l) {
    const bf16* wqkvt; const bf16* wot; const bf16* w1t; const bf16* w2t;
    if (fullprep) {
      wqkvt = WqkvT + (size_t)l * 3 * DD;
      wot   = WoT   + (size_t)l * DD;
      w1t   = W1T   + (size_t)l * DF;
      w2t   = W2T   + (size_t)l * DF;
    } else {
      prep_layer_kernel<<<3072, 256, 0, stream>>>(
          Wq + l * DD, Wk + l * DD, Wv + l * DD, Wo + l * DD,
          W1 + l * DF, W2 + l * DF, WqkvT, WoT, W1T, W2T);
      wqkvt = WqkvT; wot = WoT; w1t = W1T; w2t = W2T;
    }

    // ln1 for layers >0: fold previous FFN2 partials (np=4)
    if (l > 0)
      ln_res_kernel<<<2048, 256, 0, stream>>>(
          x, Pp, 4, b2 + (l - 1) * 1024, g1 + l * 1024, be1 + l * 1024, h);

    // QKV: M=2048 N=3072 K=1024 -> 384 blocks; fused V-transpose epilogue
    gemm_pl<4, 0><<<dim3(16, 24, 1), 256, 0, stream>>>(
        h, 1024, wqkvt, 1024, qkv, 3072, (const float*)nullptr, vT, 1024);
    attn_kernel<<<dim3(8, 32), 512, 0, stream>>>(qkv, vT, tokens, ctx);
    // Wo: M=2048 N=1024 K=1024, splitK4 -> 512 blocks, bf16 partials
    gemm_pl<3, 0><<<dim3(16, 8, 4), 256, 0, stream>>>(
        ctx, 1024, wot, 1024, Pp, 1024, (const float*)nullptr,
        (bf16*)nullptr, 256);
    // ln2: x += sum(P0..3) + bo; h = LN(x)
    ln_res_kernel<<<2048, 256, 0, stream>>>(
        x, Pp, 4, bo + l * 1024, g2 + l * 1024, be2 + l * 1024, h);
    // FFN1: M=2048 N=4096 K=1024 -> 512 blocks
    gemm_pl<2, 0><<<dim3(16, 32, 1), 256, 0, stream>>>(
        h, 1024, w1t, 1024, ff, 4096, b1 + l * 4096, (bf16*)nullptr, 1024);
    // FFN2: M=2048 N=1024 K=4096, splitK4 -> 512 blocks, bf16 partials
    gemm_pl<3, 0><<<dim3(16, 8, 4), 256, 0, stream>>>(
        ff, 4096, w2t, 4096, Pp, 1024, (const float*)nullptr,
        (bf16*)nullptr, 1024);
  }

  // final LN folds layer-5 FFN2 partials
  ln_res_kernel<<<2048, 256, 0, stream>>>(x, Pp, 4, b2 + 5 * 1024, gf, bff, h);
  // Wout transpose IMMEDIATELY before logits -> WoutT is L3-hot for gemm256
  transpose_cast_kernel<<<dim3(500, 16), 256, 0, stream>>>(Wout, WoutT, 32000, 1024);
  // logits: M=2048 N=32000 K=1024 -> 256x128 single-barrier ring, 2000 blocks
  gemm256<<<dim3(8, 250), 512, 0, stream>>>(
      h, 1024, WoutT, 1024, out, 32000, bout, 1024);
}

// Round 18
// 1200.544 us; speedup vs baseline: 1.0357x; 1.0011x over previous
//
#include <hip/hip_runtime.h>
#include <hip/hip_bf16.h>
#include <stdint.h>

typedef __hip_bfloat16 bf16;
typedef __attribute__((ext_vector_type(8))) short bf16x8;
typedef __attribute__((ext_vector_type(4))) float f32x4;
typedef __attribute__((ext_vector_type(16))) float f32x16;

#define DEV static __device__ __forceinline__

DEV float b2f(bf16 v) { return __bfloat162float(v); }
DEV bf16  f2b(float v) { return __float2bfloat16(v); }

DEV float u2f(unsigned short u) {
  unsigned int x = (unsigned int)u << 16;
  float f;
  __builtin_memcpy(&f, &x, 4);
  return f;
}

DEV unsigned short f2u(float v) {
  bf16 b = f2b(v);
  unsigned short u;
  __builtin_memcpy(&u, &b, 2);
  return u;
}

DEV void gload16(const void* g, void* l) {
  __builtin_amdgcn_global_load_lds(
      (__attribute__((address_space(1))) void*)(void*)g,
      (__attribute__((address_space(3))) void*)l, 16, 0, 0);
}

DEV f32x4 mfma16(bf16x8 a, bf16x8 b, f32x4 c) {
  return __builtin_amdgcn_mfma_f32_16x16x32_bf16(a, b, c, 0, 0, 0);
}

// 32x32x16 bf16 MFMA: C/D col=lane&31, row=(reg&3)+8*(reg>>2)+4*(lane>>5)
DEV f32x16 mfma32(bf16x8 a, bf16x8 b, f32x16 c) {
  return __builtin_amdgcn_mfma_f32_32x32x16_bf16(a, b, c, 0, 0, 0);
}

// -------- fused embed + layernorm (layer 0): x = emb[tok]*32+pe; h = LN(x) ----
__global__ __launch_bounds__(256) void embed_ln_kernel(
    const int* __restrict__ tok, const float* __restrict__ emb,
    const float* __restrict__ pe, const float* __restrict__ g,
    const float* __restrict__ be, float* __restrict__ x, bf16* __restrict__ h)
{
  const int r = blockIdx.x, t = threadIdx.x;
  const int s = r & 1023;
  const int tk = tok[r];
  const float4 e  = ((const float4*)(emb + (size_t)tk * 1024))[t];
  const float4 pp = ((const float4*)(pe + (size_t)s * 1024))[t];
  float4 v;
  v.x = e.x * 32.0f + pp.x;
  v.y = e.y * 32.0f + pp.y;
  v.z = e.z * 32.0f + pp.z;
  v.w = e.w * 32.0f + pp.w;

  float sm  = v.x + v.y + v.z + v.w;
  float sq = v.x * v.x + v.y * v.y + v.z * v.z + v.w * v.w;
  #pragma unroll
  for (int d = 1; d < 64; d <<= 1) {
    sm += __shfl_xor(sm, d);
    sq += __shfl_xor(sq, d);
  }
  __shared__ float red[8];
  const int w = t >> 6, l = t & 63;
  if (l == 0) { red[w] = sm; red[4 + w] = sq; }
  __syncthreads();
  sm = red[0] + red[1] + red[2] + red[3];
  sq = red[4] + red[5] + red[6] + red[7];
  const float mean = sm * (1.0f / 1024.0f);
  const float var  = sq * (1.0f / 1024.0f) - mean * mean;
  const float inv  = 1.0f / sqrtf(var + 1e-5f);

  ((float4*)(x + (size_t)r * 1024))[t] = v;
  bf16* hp = h + (size_t)r * 1024 + t * 4;
  const float* gp = g + t * 4;
  const float* bp = be + t * 4;
  const float vv[4] = {v.x, v.y, v.z, v.w};
  #pragma unroll
  for (int j = 0; j < 4; ++j)
    hp[j] = f2b((vv[j] - mean) * inv * gp[j] + bp[j]);
}

// -- fused residual + layernorm: x += sum(bf16 P[0..np)) + bias; h = LN(x)*g+be
__global__ __launch_bounds__(256) void ln_res_kernel(
    float* __restrict__ x, const bf16* __restrict__ P, int np,
    const float* __restrict__ bias, const float* __restrict__ g,
    const float* __restrict__ be, bf16* __restrict__ h)
{
  const int r = blockIdx.x, t = threadIdx.x;
  float4 v = ((const float4*)(x + (size_t)r * 1024))[t];
  for (int i = 0; i < np; ++i) {
    const ushort4 pv = ((const ushort4*)(P + ((size_t)i * 2048 + r) * 1024))[t];
    v.x += u2f(pv.x); v.y += u2f(pv.y); v.z += u2f(pv.z); v.w += u2f(pv.w);
  }
  const float4 bv = ((const float4*)bias)[t];
  v.x += bv.x; v.y += bv.y; v.z += bv.z; v.w += bv.w;

  float s  = v.x + v.y + v.z + v.w;
  float sq = v.x * v.x + v.y * v.y + v.z * v.z + v.w * v.w;
  #pragma unroll
  for (int d = 1; d < 64; d <<= 1) {
    s  += __shfl_xor(s, d);
    sq += __shfl_xor(sq, d);
  }
  __shared__ float red[8];
  const int w = t >> 6, l = t & 63;
  if (l == 0) { red[w] = s; red[4 + w] = sq; }
  __syncthreads();
  s  = red[0] + red[1] + red[2] + red[3];
  sq = red[4] + red[5] + red[6] + red[7];
  const float mean = s * (1.0f / 1024.0f);
  const float var  = sq * (1.0f / 1024.0f) - mean * mean;
  const float inv  = 1.0f / sqrtf(var + 1e-5f);

  ((float4*)(x + (size_t)r * 1024))[t] = v;
  bf16* hp = h + (size_t)r * 1024 + t * 4;
  const float* gp = g + t * 4;
  const float* bp = be + t * 4;
  const float vv[4] = {v.x, v.y, v.z, v.w};
  #pragma unroll
  for (int j = 0; j < 4; ++j)
    hp[j] = f2b((vv[j] - mean) * inv * gp[j] + bp[j]);
}

// ------------- 64x64 transpose+cast tile body -------------
DEV void transpose_tile(const float* __restrict__ in, bf16* __restrict__ out,
                        int ldin, int ldout, int r0, int c0, int t)
{
  __shared__ bf16 tile[64][64];
  #pragma unroll
  for (int i = 0; i < 4; ++i) {
    const int r = i * 16 + (t >> 4), c = (t & 15) * 4;
    const float4 v = *(const float4*)&in[(size_t)(r0 + r) * ldin + c0 + c];
    tile[r][c + 0] = f2b(v.x);
    tile[r][c + 1] = f2b(v.y);
    tile[r][c + 2] = f2b(v.z);
    tile[r][c + 3] = f2b(v.w);
  }
  __syncthreads();
  #pragma unroll
  for (int i = 0; i < 2; ++i) {
    const int oc = i * 32 + (t >> 3);
    const int rr = (t & 7) * 8;
    unsigned short tmp[8] __attribute__((aligned(16)));
    #pragma unroll
    for (int j = 0; j < 8; ++j)
      tmp[j] = ((const unsigned short*)tile)[(rr + j) * 64 + oc];
    *(uint4*)&out[(size_t)(c0 + oc) * ldout + r0 + rr] = *(const uint4*)tmp;
  }
}

// generic single-matrix transpose+cast (Wout, launched just before logits
// so WoutT is L3-hot when gemm256 consumes it — round-14 lesson)
__global__ __launch_bounds__(256) void transpose_cast_kernel(
    const float* __restrict__ in, bf16* __restrict__ out, int ldin, int ldout)
{
  transpose_tile(in, out, ldin, ldout, blockIdx.y * 64, blockIdx.x * 64, threadIdx.x);
}

// dispatch one 64x64 tile of the per-layer weight set (3072 tiles/layer)
DEV void prep_dispatch(int wid,
    const float* Wq, const float* Wk, const float* Wv, const float* Wo,
    const float* W1, const float* W2,
    bf16* WqkvT, bf16* WoT, bf16* W1T, bf16* W2T, int t)
{
  const float* src; bf16* dst; int ldin, ldout, tx, ty;
  if (wid < 768) {
    const int m = wid >> 8, tt = wid & 255;
    src = (m == 0) ? Wq : (m == 1) ? Wk : Wv;
    dst = WqkvT + (size_t)m * 1024 * 1024;
    ldin = 1024; ldout = 1024; tx = tt & 15; ty = tt >> 4;
  } else if (wid < 1024) {
    const int tt = wid - 768;
    src = Wo; dst = WoT; ldin = 1024; ldout = 1024; tx = tt & 15; ty = tt >> 4;
  } else if (wid < 2048) {
    const int tt = wid - 1024;
    src = W1; dst = W1T; ldin = 4096; ldout = 1024; tx = tt & 63; ty = tt >> 6;
  } else {
    const int tt = wid - 2048;
    src = W2; dst = W2T; ldin = 1024; ldout = 4096; tx = tt & 15; ty = tt >> 4;
  }
  transpose_tile(src, dst, ldin, ldout, ty * 64, tx * 64, t);
}

// per-layer weight prep (fallback path)
__global__ __launch_bounds__(256) void prep_layer_kernel(
    const float* __restrict__ Wq, const float* __restrict__ Wk,
    const float* __restrict__ Wv, const float* __restrict__ Wo,
    const float* __restrict__ W1, const float* __restrict__ W2,
    bf16* __restrict__ WqkvT, bf16* __restrict__ WoT,
    bf16* __restrict__ W1T, bf16* __restrict__ W2T)
{
  prep_dispatch(blockIdx.x, Wq, Wk, Wv, Wo, W1, W2,
                WqkvT, WoT, W1T, W2T, threadIdx.x);
}

// all-layers weight prep: 6*3072 blocks (Wout handled separately pre-logits)
__global__ __launch_bounds__(256) void prep_all_kernel(
    const float* __restrict__ Wq, const float* __restrict__ Wk,
    const float* __restrict__ Wv, const float* __restrict__ Wo,
    const float* __restrict__ W1, const float* __restrict__ W2,
    bf16* __restrict__ WqkvT, bf16* __restrict__ WoT,
    bf16* __restrict__ W1T, bf16* __restrict__ W2T)
{
  const size_t DD = (size_t)1024 * 1024, DF = (size_t)1024 * 4096;
  const int layer = blockIdx.x / 3072;
  const int wid = blockIdx.x - layer * 3072;
  prep_dispatch(wid,
      Wq + layer * DD, Wk + layer * DD, Wv + layer * DD, Wo + layer * DD,
      W1 + layer * DF, W2 + layer * DF,
      WqkvT + layer * 3 * DD, WoT + layer * DD,
      W1T + layer * DF, W2T + layer * DF, threadIdx.x);
}

// ------------- pipelined GEMM: C(MxN) = A(MxK,row) * BT(NxK,row)^T -------------
// BM=BN=128, BK=32; 3-buffer single-barrier ring (48 KB LDS -> 3 blocks/CU),
// counted vmcnt(4) (T4). MFMA 32x32x16 (round-16 win).
// EPI: 0 = bf16 store; 1 = +bias f32 store; 2 = gelu(acc+bias) bf16;
//      3 = bf16 K-slice partial store P[z][M][N]; 4 = QKV fused: cols<2048 ->
//          qkv bf16, cols>=2048 -> vT[(b*1024+hk)*1024+s] transposed write
// grid: (M/128, N/128, KSLICES), block 256 (4 waves), K-slice length ksl
template<int EPI, int SWZ>
__global__ __launch_bounds__(256, 3) void gemm_pl(
    const bf16* __restrict__ A, int lda,
    const bf16* __restrict__ BT, int ldb,
    void* __restrict__ Cp, int ldc,
    const float* __restrict__ bias,
    bf16* __restrict__ vTp,
    int ksl)
{
  __shared__ bf16 As[3][4096];
  __shared__ bf16 Bs[3][4096];
  const int t = threadIdx.x;

  int bm, bn;
  if constexpr (SWZ) {
    const int nbm = gridDim.x;
    const int nwg = nbm * gridDim.y;
    int wid = blockIdx.x + nbm * blockIdx.y;
    wid = (wid & 7) * (nwg >> 3) + (wid >> 3);
    bm = wid % nbm; bn = wid / nbm;
  } else {
    bm = blockIdx.x; bn = blockIdx.y;
  }

  const int w = t >> 6, l = t & 63;
  const int wr = (w >> 1) * 64, wc = (w & 1) * 64;
  const int l31 = l & 31, l5 = l >> 5;
  const int kbeg = blockIdx.z * ksl;
  const int NT = ksl >> 5;

  const int colblk = (((t & 3) ^ ((t >> 3) & 3))) * 8;
  const bf16* gA = A  + (size_t)(bm * 128 + (t >> 2)) * lda + colblk + kbeg;
  const bf16* gB = BT + (size_t)(bn * 128 + (t >> 2)) * ldb + colblk + kbeg;
  const int dst = w * 512;

  auto stage = [&](int tile, int buf) {
    const int k0 = tile * 32;
    gload16(gA + k0, &As[buf][dst]);
    gload16(gA + (size_t)64 * lda + k0, &As[buf][2048 + dst]);
    gload16(gB + k0, &Bs[buf][dst]);
    gload16(gB + (size_t)64 * ldb + k0, &Bs[buf][2048 + dst]);
  };

  f32x16 acc[2][2];
  #pragma unroll
  for (int m = 0; m < 2; ++m)
    #pragma unroll
    for (int n = 0; n < 2; ++n)
      acc[m][n] = (f32x16)(0.f);

  stage(0, 0);
  stage(1, 1);

  const int key = (l31 >> 1) & 3;
  const int rd0 = ((l5)     ^ key) * 8;   // ks=0 col-block
  const int rd1 = ((2 + l5) ^ key) * 8;   // ks=1 col-block

  int buf = 0;
  for (int kt = 0; kt < NT; ++kt) {
    if (kt + 1 < NT) asm volatile("s_waitcnt vmcnt(4)" ::: "memory");
    else             asm volatile("s_waitcnt vmcnt(0)" ::: "memory");
    __builtin_amdgcn_s_barrier();
    __builtin_amdgcn_sched_barrier(0);

    int nb = buf + 2; if (nb >= 3) nb -= 3;

    bf16x8 a0[2], a1[2], b0[2], b1[2];
    #pragma unroll
    for (int m = 0; m < 2; ++m) {
      const int row = (wr + m * 32 + l31) * 32;
      a0[m] = *(const bf16x8*)&As[buf][row + rd0];
      a1[m] = *(const bf16x8*)&As[buf][row + rd1];
    }
    #pragma unroll
    for (int n = 0; n < 2; ++n) {
      const int row = (wc + n * 32 + l31) * 32;
      b0[n] = *(const bf16x8*)&Bs[buf][row + rd0];
      b1[n] = *(const bf16x8*)&Bs[buf][row + rd1];
    }
    if (kt + 2 < NT) stage(kt + 2, nb);
    asm volatile("s_waitcnt lgkmcnt(0)" ::: "memory");
    __builtin_amdgcn_sched_barrier(0);

    __builtin_amdgcn_s_setprio(1);
    #pragma unroll
    for (int m = 0; m < 2; ++m)
      #pragma unroll
      for (int n = 0; n < 2; ++n) {
        acc[m][n] = mfma32(a0[m], b0[n], acc[m][n]);
        acc[m][n] = mfma32(a1[m], b1[n], acc[m][n]);
      }
    __builtin_amdgcn_s_setprio(0);
    __builtin_amdgcn_sched_barrier(0);

    if (++buf >= 3) buf = 0;
  }

  const int crow = bm * 128 + wr, ccol = bn * 128 + wc;
  #pragma unroll
  for (int n = 0; n < 2; ++n) {
    const int col = ccol + n * 32 + l31;
    float bv = 0.f;
    if (EPI == 1 || EPI == 2) bv = bias[col];
    #pragma unroll
    for (int m = 0; m < 2; ++m) {
      #pragma unroll
      for (int gq = 0; gq < 4; ++gq) {
        const int row = crow + m * 32 + gq * 8 + l5 * 4;
        if (EPI == 4 && ccol >= 2048) {
          const int b = row >> 10, s = row & 1023;
          const int hk = col - 2048;
          ushort4 pk;
          pk.x = f2u(acc[m][n][gq * 4 + 0]);
          pk.y = f2u(acc[m][n][gq * 4 + 1]);
          pk.z = f2u(acc[m][n][gq * 4 + 2]);
          pk.w = f2u(acc[m][n][gq * 4 + 3]);
          *(ushort4*)&vTp[((size_t)b * 1024 + hk) * 1024 + s] = pk;
          continue;
        }
        #pragma unroll
        for (int r = 0; r < 4; ++r) {
          const float v = acc[m][n][gq * 4 + r];
          if (EPI == 0 || EPI == 4) {
            ((bf16*)Cp)[(size_t)(row + r) * ldc + col] = f2b(v);
          } else if (EPI == 1) {
            ((float*)Cp)[(size_t)(row + r) * ldc + col] = v + bv;
          } else if (EPI == 2) {
            const float u = v + bv;
            const float gel = 0.5f * u * (1.0f + erff(u * 0.70710678118654752f));
            ((bf16*)Cp)[(size_t)(row + r) * ldc + col] = f2b(gel);
          } else {
            const int M = gridDim.x * 128;
            ((bf16*)Cp)[((size_t)blockIdx.z * M + row + r) * ldc + col] = f2b(v);
          }
        }
      }
    }
  }
}

// ------------- 256x128 8-wave single-barrier GEMM (logits; best measured) ----
__global__ __launch_bounds__(512, 4) void gemm256(
    const bf16* __restrict__ A, int lda,
    const bf16* __restrict__ BT, int ldb,
    float* __restrict__ C, int ldc,
    const float* __restrict__ bias, int K)
{
  __shared__ bf16 As[3][8192];
  __shared__ bf16 Bs[3][4096];
  const int t = threadIdx.x;

  const int nbm = gridDim.x;
  const int nwg = nbm * gridDim.y;
  int wid = blockIdx.x + nbm * blockIdx.y;
  wid = (wid & 7) * (nwg >> 3) + (wid >> 3);
  const int bm = wid % nbm, bn = wid / nbm;

  const int w = t >> 6, l = t & 63;
  const int wm = w >> 1, wn = w & 1;
  const int l15 = l & 15, l4 = l >> 4;

  const int colblk = ((t & 3) ^ ((t >> 3) & 3)) * 8;
  const bf16* gA = A  + (size_t)(bm * 256 + (t >> 2)) * lda + colblk;
  const bf16* gB = BT + (size_t)(bn * 128 + (t >> 2)) * ldb + colblk;
  const int dst = w * 512;

  auto stage = [&](int kt, int buf) {
    const int k0 = kt * 32;
    gload16(gA + k0, &As[buf][dst]);
    gload16(gA + (size_t)128 * lda + k0, &As[buf][4096 + dst]);
    gload16(gB + k0, &Bs[buf][dst]);
  };

  const int rd = (l4 ^ ((l15 >> 1) & 3)) * 8;
  const int arow = wm * 64 + l15;
  const int brow = wn * 64 + l15;

  f32x4 acc[4][4];
  #pragma unroll
  for (int m = 0; m < 4; ++m)
    #pragma unroll
    for (int n = 0; n < 4; ++n)
      acc[m][n] = (f32x4){0.f, 0.f, 0.f, 0.f};

  const int NT = K >> 5;
  stage(0, 0);
  stage(1, 1);

  int buf = 0;
  for (int kt = 0; kt < NT; ++kt) {
    if (kt + 1 < NT) asm volatile("s_waitcnt vmcnt(3)" ::: "memory");
    else             asm volatile("s_waitcnt vmcnt(0)" ::: "memory");
    __builtin_amdgcn_s_barrier();
    __builtin_amdgcn_sched_barrier(0);

    int nb = buf + 2; if (nb >= 3) nb -= 3;

    bf16x8 af[4], bfr[4];
    #pragma unroll
    for (int n = 0; n < 4; ++n)
      bfr[n] = *(const bf16x8*)&Bs[buf][(brow + n * 16) * 32 + rd];
    #pragma unroll
    for (int m = 0; m < 4; ++m)
      af[m] = *(const bf16x8*)&As[buf][(arow + m * 16) * 32 + rd];
    if (kt + 2 < NT) stage(kt + 2, nb);
    asm volatile("s_waitcnt lgkmcnt(0)" ::: "memory");
    __builtin_amdgcn_sched_barrier(0);

    __builtin_amdgcn_s_setprio(1);
    #pragma unroll
    for (int m = 0; m < 4; ++m)
      #pragma unroll
      for (int n = 0; n < 4; ++n)
        acc[m][n] = mfma16(af[m], bfr[n], acc[m][n]);
    __builtin_amdgcn_s_setprio(0);
    __builtin_amdgcn_sched_barrier(0);

    if (++buf >= 3) buf = 0;
  }

  #pragma unroll
  for (int n = 0; n < 4; ++n) {
    const int col = bn * 128 + wn * 64 + n * 16 + l15;
    const float bv = bias[col];
    #pragma unroll
    for (int m = 0; m < 4; ++m) {
      const int row = bm * 256 + wm * 64 + m * 16 + l4 * 4;
      #pragma unroll
      for (int r = 0; r < 4; ++r)
        C[(size_t)(row + r) * ldc + col] = acc[m][n][r] + bv;
    }
  }
}

// ---------------- flash attention (4 waves x 16 q-rows = 64-row blocks) ----
// grid: 512 linear blocks, 256 threads, 48 KB LDS -> 2-3 blocks/CU resident.
// Complementary pairing: CU c gets blocks c and c+256 whose KV-iteration
// counts sum to ~const (qh and 15-qh) -> balanced makespan + TLP overlap.
__global__ __launch_bounds__(256) void attn_kernel(
    const bf16* __restrict__ qkv, const bf16* __restrict__ vT,
    const int* __restrict__ tokens, bf16* __restrict__ ctx)
{
  __shared__ bf16 Ks[128 * 64];
  __shared__ bf16 VTs[64 * 128];
  __shared__ bf16 Ps[64 * 128];

  const int wid = blockIdx.x;
  const int half = wid >> 8;                 // 0 or 1
  const int rr0 = wid & 255;
  const int bh = rr0 >> 3;                   // 32 (b,h) groups
  const int qh = half ? (15 - (rr0 & 7)) : (rr0 & 7);  // 16 half-tiles
  const int b = bh >> 4, h = bh & 15;
  const int t = threadIdx.x, w = t >> 6, l = t & 63;
  const int l15 = l & 15, l4 = l >> 4;
  const int q0 = qh * 64;

  bf16x8 aq[2];
  #pragma unroll
  for (int ks = 0; ks < 2; ++ks)
    aq[ks] = *(const bf16x8*)(qkv +
        (size_t)(b * 1024 + q0 + w * 16 + l15) * 3072 +
        h * 64 + ks * 32 + l4 * 8);

  f32x4 o[4];
  float m_run[4], l_run[4];
  #pragma unroll
  for (int r = 0; r < 4; ++r) { m_run[r] = -1e30f; l_run[r] = 0.f; }
  #pragma unroll
  for (int nn = 0; nn < 4; ++nn)
    o[nn] = (f32x4){0.f, 0.f, 0.f, 0.f};

  const bf16* kb = qkv + (size_t)(b * 1024) * 3072 + 1024 + h * 64;
  const bf16* vb = vT + (size_t)(bh * 64) * 1024;
  const int* tb = tokens + b * 1024;

  // staging swizzle (pre-swizzled global source, linear LDS dest; 256 threads)
  const int kSrcCol = ((t & 7) ^ ((t >> 3) & 7)) * 8;   // K key: row&7
  const int vSrcCol = ((t & 15) ^ (t >> 4)) * 8;        // V key: row&15

  const int nt = (qh >> 1) + 1;              // causal KV tiles for rows q0..q0+63
  for (int jt = 0; jt < nt; ++jt) {
    const int j0 = jt * 128;
    __syncthreads();  // previous iteration's LDS reads complete
    #pragma unroll
    for (int i = 0; i < 4; ++i)
      gload16(kb + (size_t)(j0 + i * 32 + (t >> 3)) * 3072 + kSrcCol,
              Ks + i * 2048 + w * 512);
    #pragma unroll
    for (int i = 0; i < 4; ++i)
      gload16(vb + (size_t)(i * 16 + (t >> 4)) * 1024 + j0 + vSrcCol,
              VTs + i * 2048 + w * 512);
    __syncthreads();  // staged tiles visible

    // S = Q K^T for this wave's 16 rows x 128 cols
    f32x4 s[8];
    #pragma unroll
    for (int n = 0; n < 8; ++n)
      s[n] = (f32x4){0.f, 0.f, 0.f, 0.f};
    #pragma unroll
    for (int ks = 0; ks < 2; ++ks) {
      #pragma unroll
      for (int n = 0; n < 8; ++n) {
        const bf16x8 bk = *(const bf16x8*)
            &Ks[(n * 16 + l15) * 64 + ((ks * 32 + l4 * 8) ^ ((l15 & 7) * 8))];
        s[n] = mfma16(aq[ks], bk, s[n]);
      }
    }

    float padv[8];
    #pragma unroll
    for (int n = 0; n < 8; ++n)
      padv[n] = (tb[j0 + n * 16 + l15] == 0) ? 1.f : 0.f;

    // online softmax per q-row; write P to LDS (swizzled, wave-local rows)
    #pragma unroll
    for (int r = 0; r < 4; ++r) {
      const int rloc = l4 * 4 + r;
      const int qrow = q0 + w * 16 + rloc;
      float vals[8];
      float mx = -1e30f;
      #pragma unroll
      for (int n = 0; n < 8; ++n) {
        const int jg = j0 + n * 16 + l15;
        float v = s[n][r] * 0.125f;
        if (jg > qrow || padv[n] != 0.f) v = -1e9f;
        vals[n] = v;
        mx = fmaxf(mx, v);
      }
      #pragma unroll
      for (int d = 1; d < 16; d <<= 1) mx = fmaxf(mx, __shfl_xor(mx, d));
      const float newm = fmaxf(m_run[r], mx);
      const float sc = __expf(m_run[r] - newm);
      m_run[r] = newm;
      float rs = 0.f;
      #pragma unroll
      for (int n = 0; n < 8; ++n) {
        const float pv = __expf(vals[n] - newm);
        vals[n] = pv;
        rs += pv;
      }
      #pragma unroll
      for (int d = 1; d < 16; d <<= 1) rs += __shfl_xor(rs, d);
      l_run[r] = l_run[r] * sc + rs;
      #pragma unroll
      for (int nn = 0; nn < 4; ++nn) o[nn][r] = o[nn][r] * sc;
      #pragma unroll
      for (int n = 0; n < 8; ++n)
        Ps[(w * 16 + rloc) * 128 + ((n * 16 + l15) ^ (rloc * 8))] = f2b(vals[n]);
    }
    // wave-local P rows: only our own ds_writes must complete
    asm volatile("s_waitcnt lgkmcnt(0)" ::: "memory");

    // O += P V
    #pragma unroll
    for (int ks = 0; ks < 4; ++ks) {
      const bf16x8 ap = *(const bf16x8*)
          &Ps[(w * 16 + l15) * 128 + ((ks * 32 + l4 * 8) ^ (l15 * 8))];
      #pragma unroll
      for (int nn = 0; nn < 4; ++nn) {
        const bf16x8 bv = *(const bf16x8*)
            &VTs[(nn * 16 + l15) * 128 + ((ks * 32 + l4 * 8) ^ (l15 * 8))];
        o[nn] = mfma16(ap, bv, o[nn]);
      }
    }
  }

  // epilogue: ctx = O / l
  #pragma unroll
  for (int r = 0; r < 4; ++r) {
    const float inv = 1.0f / l_run[r];
    const int qrow = q0 + w * 16 + l4 * 4 + r;
    #pragma unroll
    for (int nn = 0; nn < 4; ++nn)
      ctx[(size_t)(b * 1024 + qrow) * 1024 + h * 64 + nn * 16 + l15] =
          f2b(o[nn][r] * inv);
  }

  // fused fixup: rows < P0 (leading pads) -> ctx = mean over all S of V.
  int loc = 1024;
  #pragma unroll 4
  for (int j = 0; j < 16; ++j) {
    const int idx = l * 16 + j;
    if (tb[idx] != 0) { loc = idx; break; }
  }
  #pragma unroll
  for (int d = 1; d < 64; d <<= 1) {
    const int o2 = __shfl_xor(loc, d);
    loc = (o2 < loc) ? o2 : loc;
  }
  const int P0 = loc;
  if (P0 > q0) {
    __syncthreads();
    const int rbeg = q0 + w * 16;
    if (P0 > rbeg) {
      const bf16* vrow = vb + (size_t)l * 1024;
      float sum = 0.f;
      for (int sIdx = 0; sIdx < 1024; sIdx += 4) {
        const ushort4 pv = *(const ushort4*)&vrow[sIdx];
        sum += u2f(pv.x) + u2f(pv.y) + u2f(pv.z) + u2f(pv.w);
      }
      const bf16 mv = f2b(sum * (1.0f / 1024.0f));
      const int rend = (P0 < rbeg + 16) ? P0 : (rbeg + 16);
      for (int q = rbeg; q < rend; ++q)
        ctx[(size_t)(b * 1024 + q) * 1024 + h * 64 + l] = mv;
    }
  }
}

// ---------------- host ----------------
extern "C" void kernel_launch(void* const* d_in, const int* in_sizes, int n_in,
                              void* d_out, int out_size, void* d_ws, size_t ws_size,
                              hipStream_t stream)
{
  (void)in_sizes; (void)n_in; (void)out_size;
  const int*   tokens = (const int*)d_in[0];
  const float* emb  = (const float*)d_in[1];
  const float* pe   = (const float*)d_in[2];
  const float* Wq   = (const float*)d_in[3];
  const float* Wk   = (const float*)d_in[4];
  const float* Wv   = (const float*)d_in[5];
  const float* Wo   = (const float*)d_in[6];
  const float* bo   = (const float*)d_in[7];
  const float* g1   = (const float*)d_in[8];
  const float* be1  = (const float*)d_in[9];
  const float* g2   = (const float*)d_in[10];
  const float* be2  = (const float*)d_in[11];
  const float* W1   = (const float*)d_in[12];
  const float* b1   = (const float*)d_in[13];
  const float* W2   = (const float*)d_in[14];
  const float* b2   = (const float*)d_in[15];
  const float* gf   = (const float*)d_in[16];
  const float* bff  = (const float*)d_in[17];
  const float* Wout = (const float*)d_in[18];
  const float* bout = (const float*)d_in[19];
  float* out = (float*)d_out;

  char* p = (char*)d_ws;
  auto alloc = [&](size_t bytes) {
    char* q = p;
    p += (bytes + 255) & ~(size_t)255;
    return q;
  };
  float* x    = (float*)alloc((size_t)2048 * 1024 * 4);
  bf16* Pp    = (bf16*)alloc((size_t)4 * 2048 * 1024 * 2);
  bf16* h     = (bf16*)alloc((size_t)2048 * 1024 * 2);
  bf16* qkv   = (bf16*)alloc((size_t)2048 * 3072 * 2);
  bf16* vT    = (bf16*)alloc((size_t)2048 * 1024 * 2);
  bf16* ctx   = (bf16*)alloc((size_t)2048 * 1024 * 2);
  bf16* ff    = (bf16*)alloc((size_t)2048 * 4096 * 2);
  bf16* WoutT = (bf16*)alloc((size_t)32000 * 1024 * 2);

  const size_t DD = (size_t)1024 * 1024;
  const size_t DF = (size_t)1024 * 4096;

  const size_t perLayerW = (3 * DD + DD + DF + DF) * 2;
  const size_t used = (size_t)(p - (char*)d_ws);
  const bool fullprep = ws_size >= used + 6 * perLayerW + 8192;
  const int NL = fullprep ? 6 : 1;
  bf16* WqkvT = (bf16*)alloc((size_t)NL * 3 * DD * 2);
  bf16* WoT   = (bf16*)alloc((size_t)NL * DD * 2);
  bf16* W1T   = (bf16*)alloc((size_t)NL * DF * 2);
  bf16* W2T   = (bf16*)alloc((size_t)NL * DF * 2);

  if (fullprep)
    prep_all_kernel<<<6 * 3072, 256, 0, stream>>>(
        Wq, Wk, Wv, Wo, W1, W2, WqkvT, WoT, W1T, W2T);

  // fused embed + ln1(layer 0)
  embed_ln_kernel<<<2048, 256, 0, stream>>>(tokens, emb, pe, g1, be1, x, h);

  for (int l = 0; l < 6; ++l) {
    const bf16* wqkvt; const bf16* wot; const bf16* w1t; const bf16* w2t;
    if (fullprep) {
      wqkvt = WqkvT + (size_t)l * 3 * DD;
      wot   = WoT   + (size_t)l * DD;
      w1t   = W1T   + (size_t)l * DF;
      w2t   = W2T   + (size_t)l * DF;
    } else {
      prep_layer_kernel<<<3072, 256, 0, stream>>>(
          Wq + l * DD, Wk + l * DD, Wv + l * DD, Wo + l * DD,
          W1 + l * DF, W2 + l * DF, WqkvT, WoT, W1T, W2T);
      wqkvt = WqkvT; wot = WoT; w1t = W1T; w2t = W2T;
    }

    // ln1 for layers >0: fold previous FFN2 partials (np=4)
    if (l > 0)
      ln_res_kernel<<<2048, 256, 0, stream>>>(
          x, Pp, 4, b2 + (l - 1) * 1024, g1 + l * 1024, be1 + l * 1024, h);

    // QKV: M=2048 N=3072 K=1024 -> 384 blocks; fused V-transpose epilogue
    gemm_pl<4, 0><<<dim3(16, 24, 1), 256, 0, stream>>>(
        h, 1024, wqkvt, 1024, qkv, 3072, (const float*)nullptr, vT, 1024);
    // attn: 512 balanced 64-row blocks, 2-3 blocks/CU
    attn_kernel<<<512, 256, 0, stream>>>(qkv, vT, tokens, ctx);
    // Wo: M=2048 N=1024 K=1024, splitK4 -> 512 blocks, bf16 partials
    gemm_pl<3, 0><<<dim3(16, 8, 4), 256, 0, stream>>>(
        ctx, 1024, wot, 1024, Pp, 1024, (const float*)nullptr,
        (bf16*)nullptr, 256);
    // ln2: x += sum(P0..3) + bo; h = LN(x)
    ln_res_kernel<<<2048, 256, 0, stream>>>(
        x, Pp, 4, bo + l * 1024, g2 + l * 1024, be2 + l * 1024, h);
    // FFN1: M=2048 N=4096 K=1024 -> 512 blocks
    gemm_pl<2, 0><<<dim3(16, 32, 1), 256, 0, stream>>>(
        h, 1024, w1t, 1024, ff, 4096, b1 + l * 4096, (bf16*)nullptr, 1024);
    // FFN2: M=2048 N=1024 K=4096, splitK4 -> 512 blocks, bf16 partials
    gemm_pl<3, 0><<<dim3(16, 8, 4), 256, 0, stream>>>(
        ff, 4096, w2t, 4096, Pp, 1024, (const float*)nullptr,
        (bf16*)nullptr, 1024);
  }

  // final LN folds layer-5 FFN2 partials
  ln_res_kernel<<<2048, 256, 0, stream>>>(x, Pp, 4, b2 + 5 * 1024, gf, bff, h);
  // Wout transpose IMMEDIATELY before logits -> WoutT is L3-hot for gemm256
  transpose_cast_kernel<<<dim3(500, 16), 256, 0, stream>>>(Wout, WoutT, 32000, 1024);
  // logits: M=2048 N=32000 K=1024 -> 256x128 single-barrier ring, 2000 blocks
  gemm256<<<dim3(8, 250), 512, 0, stream>>>(
      h, 1024, WoutT, 1024, out, 32000, bout, 1024);
}